// Round 3
// baseline (893.700 us; speedup 1.0000x reference)
//
#include <hip/hip_runtime.h>
#include <stdint.h>

#define NPTS 512
#define DIN  8192
#define HENC 2048
#define EMB  256
#define HDEC 2048
#define BR   128
#define ETA  2.0f
#define RTOL 1e-4f
#define ATOLC 1e-8f

typedef __attribute__((ext_vector_type(8))) short bf16x8;
typedef __attribute__((ext_vector_type(4))) float f32x4;

__device__ __forceinline__ unsigned short f2bf(float f) {
    unsigned int x = __builtin_bit_cast(unsigned int, f);
    unsigned int lsb = (x >> 16) & 1u;
    x += 0x7fffu + lsb;
    return (unsigned short)(x >> 16);
}

// DPP-based wave64 min-reduce (VALU-latency cross-lane; avoids ds_bpermute ~120cyc).
template<int CTRL>
__device__ __forceinline__ float dppmin_f(float x) {
    int xi = __builtin_bit_cast(int, x);
    int f = __builtin_amdgcn_update_dpp(xi, xi, CTRL, 0xf, 0xf, false);
    return fminf(x, __builtin_bit_cast(float, f));
}
__device__ __forceinline__ float wavemin_f(float x) {
    x = dppmin_f<0x111>(x);  // row_shr:1
    x = dppmin_f<0x112>(x);  // row_shr:2
    x = dppmin_f<0x114>(x);  // row_shr:4
    x = dppmin_f<0x118>(x);  // row_shr:8
    x = dppmin_f<0x142>(x);  // row_bcast:15
    x = dppmin_f<0x143>(x);  // row_bcast:31
    return x;
}

__global__ void k_init(float* acc) {
    if (threadIdx.x < 4) acc[threadIdx.x] = 0.0f;
}

// ============ bf16 MFMA GEMM v3: 64x64 tile, BK=32, LDS dbuf, prefetch-2, optional K-split ============
// OUT==0: Cf = relu(A@B+bias) f32   (GEMM1: h1)
// OUT==1: Cb = bf16(relu(A@B+bias)) (GEMM3: h2b)
// OUT==2: acc += sum((X-(A@B+bias))^2) (GEMM4, recon never stored)
// A_BF16==1: A is bf16 ushort; else f32 converted in staging.
// SPLIT==1: 512 threads, two 256-thread halves each do K/2 with own LDS dbuf, LDS-reduce at end.
template<int OUT, int A_BF16, int SPLIT>
__global__ __launch_bounds__(SPLIT ? 512 : 256) void k_mfma(
    const void* __restrict__ Araw,
    const float* __restrict__ B,
    const float* __restrict__ bias,
    float* __restrict__ Cf,
    unsigned short* __restrict__ Cb,
    const float* __restrict__ X,
    float* __restrict__ acc,
    int Nn, int K)
{
    __shared__ unsigned short As[SPLIT ? 2 : 1][2][64 * 40];  // [sub][buf][m*40+k]
    __shared__ unsigned int   Bd[SPLIT ? 2 : 1][2][64 * 20];  // [sub][buf][n*20+kd]
    __shared__ float          red[SPLIT ? 4096 : 1];
    const int t = threadIdx.x;
    const int sub = SPLIT ? (t >> 8) : 0;
    const int tt = SPLIT ? (t & 255) : t;
    const int w = tt >> 6;
    const int l = tt & 63;
    const int quad = l >> 4;
    const int r16 = l & 15;
    const int n0 = blockIdx.x * 64;
    const int m0 = blockIdx.y * 64;

    const int ar = tt >> 2, ac = (tt & 3) * 8;     // A staging
    const int kp = tt & 15, n4 = (tt >> 4) * 4;    // B staging

    const int kb = sub * (K >> SPLIT);
    const int ke = kb + (K >> SPLIT);

    f32x4 c0 = {0,0,0,0}, c1 = {0,0,0,0}, c2 = {0,0,0,0}, c3 = {0,0,0,0};

    int4   aI_0, aI_1;
    float4 aF0_0, aF1_0, bR0_0, bR1_0;
    float4 aF0_1, aF1_1, bR0_1, bR1_1;

    #define LOAD_T(S, k0)                                                              \
        do {                                                                           \
            if (A_BF16) {                                                              \
                const unsigned short* A = (const unsigned short*)Araw;                 \
                aI_##S = *(const int4*)(A + (size_t)(m0 + ar) * K + (k0) + ac);        \
            } else {                                                                   \
                const float* A = (const float*)Araw;                                   \
                aF0_##S = *(const float4*)(A + (size_t)(m0 + ar) * K + (k0) + ac);     \
                aF1_##S = *(const float4*)(A + (size_t)(m0 + ar) * K + (k0) + ac + 4); \
            }                                                                          \
            bR0_##S = *(const float4*)(B + (size_t)((k0) + 2 * kp) * Nn + n0 + n4);    \
            bR1_##S = *(const float4*)(B + (size_t)((k0) + 2 * kp + 1) * Nn + n0 + n4);\
        } while (0)

    #define STORE_T(S, buf)                                                            \
        do {                                                                           \
            if (A_BF16) {                                                              \
                *(int4*)(&As[sub][buf][ar * 40 + ac]) = aI_##S;                        \
            } else {                                                                   \
                int4 p;                                                                \
                p.x = (int)(((unsigned)f2bf(aF0_##S.y) << 16) | f2bf(aF0_##S.x));      \
                p.y = (int)(((unsigned)f2bf(aF0_##S.w) << 16) | f2bf(aF0_##S.z));      \
                p.z = (int)(((unsigned)f2bf(aF1_##S.y) << 16) | f2bf(aF1_##S.x));      \
                p.w = (int)(((unsigned)f2bf(aF1_##S.w) << 16) | f2bf(aF1_##S.z));      \
                *(int4*)(&As[sub][buf][ar * 40 + ac]) = p;                             \
            }                                                                          \
            const float bl[4] = {bR0_##S.x, bR0_##S.y, bR0_##S.z, bR0_##S.w};          \
            const float bh[4] = {bR1_##S.x, bR1_##S.y, bR1_##S.z, bR1_##S.w};          \
            _Pragma("unroll")                                                          \
            for (int i = 0; i < 4; ++i)                                                \
                Bd[sub][buf][(n4 + i) * 20 + kp] =                                     \
                    ((unsigned)f2bf(bh[i]) << 16) | f2bf(bl[i]);                       \
        } while (0)

    #define COMP(buf)                                                                  \
        do {                                                                           \
            bf16x8 bf = *(const bf16x8*)(&Bd[sub][buf][(w * 16 + r16) * 20 + quad * 4]);\
            bf16x8 a0 = *(const bf16x8*)(&As[sub][buf][(0  + r16) * 40 + quad * 8]);   \
            bf16x8 a1 = *(const bf16x8*)(&As[sub][buf][(16 + r16) * 40 + quad * 8]);   \
            bf16x8 a2 = *(const bf16x8*)(&As[sub][buf][(32 + r16) * 40 + quad * 8]);   \
            bf16x8 a3 = *(const bf16x8*)(&As[sub][buf][(48 + r16) * 40 + quad * 8]);   \
            c0 = __builtin_amdgcn_mfma_f32_16x16x32_bf16(a0, bf, c0, 0, 0, 0);         \
            c1 = __builtin_amdgcn_mfma_f32_16x16x32_bf16(a1, bf, c1, 0, 0, 0);         \
            c2 = __builtin_amdgcn_mfma_f32_16x16x32_bf16(a2, bf, c2, 0, 0, 0);         \
            c3 = __builtin_amdgcn_mfma_f32_16x16x32_bf16(a3, bf, c3, 0, 0, 0);         \
        } while (0)

    // prologue: tiles kb, kb+32 in flight; tile kb staged to buf0
    LOAD_T(0, kb);
    LOAD_T(1, kb + 32);
    STORE_T(0, 0);
    int cur = 0;
    // main loop: two tiles per trip, one barrier per tile
    for (int k0 = kb; k0 < ke; k0 += 64) {
        if (k0 + 64 < ke) LOAD_T(0, k0 + 64);
        __syncthreads();            // buf[cur] (tile k0) ready; prior reads of buf[cur^1] done
        COMP(cur);
        STORE_T(1, cur ^ 1);        // tile k0+32 (loads issued one tile ago)
        cur ^= 1;
        if (k0 + 96 < ke) LOAD_T(1, k0 + 96);
        __syncthreads();            // buf[cur] (tile k0+32) ready
        COMP(cur);
        if (k0 + 64 < ke) { STORE_T(0, cur ^ 1); cur ^= 1; }
    }
    #undef LOAD_T
    #undef STORE_T
    #undef COMP

    f32x4 frags[4] = {c0, c1, c2, c3};

    if (SPLIT) {
        if (sub == 1) {
            #pragma unroll
            for (int f = 0; f < 4; ++f)
                #pragma unroll
                for (int rg = 0; rg < 4; ++rg)
                    red[(f * 16 + quad * 4 + rg) * 64 + w * 16 + r16] = frags[f][rg];
        }
        __syncthreads();
        if (sub == 1) return;
        #pragma unroll
        for (int f = 0; f < 4; ++f)
            #pragma unroll
            for (int rg = 0; rg < 4; ++rg)
                frags[f][rg] += red[(f * 16 + quad * 4 + rg) * 64 + w * 16 + r16];
    }

    const int col = n0 + w * 16 + r16;
    const float bval = bias[col];
    float local = 0.f;
    #pragma unroll
    for (int f = 0; f < 4; ++f) {
        #pragma unroll
        for (int rg = 0; rg < 4; ++rg) {
            const int row = m0 + f * 16 + quad * 4 + rg;  // C/D: col=lane&15, row=quad*4+reg (m89)
            const float v = frags[f][rg] + bval;
            if (OUT == 0) {
                Cf[(size_t)row * Nn + col] = fmaxf(v, 0.f);
            } else if (OUT == 1) {
                Cb[(size_t)row * Nn + col] = f2bf(fmaxf(v, 0.f));
            } else {
                const float d = X[(size_t)row * Nn + col] - v;
                local += d * d;
            }
        }
    }
    if (OUT == 2) {
        #pragma unroll
        for (int off = 32; off; off >>= 1) local += __shfl_xor(local, off);
        if (l == 0) atomicAdd(acc, local);
    }
}

// ============ GEMM2 (latent = h1@We2+b2), fp32 VALU, 64x64 tile, in-block 2-way K-split ============
__global__ __launch_bounds__(512) void k_gemm2(
    const float* __restrict__ A,     // [512,2048]
    const float* __restrict__ B,     // [2048,256]
    const float* __restrict__ bias,  // [256]
    float* __restrict__ C)           // [512,256]
{
    __shared__ float AT[2][32 * 68];
    __shared__ float Bs[2][32 * 68];
    __shared__ float red[64 * 64];
    const int t = threadIdx.x;
    const int sub = t >> 8, tt = t & 255;
    const int m0 = blockIdx.y * 64, n0 = blockIdx.x * 64;
    const int ti = tt >> 4, tj = tt & 15;
    const int ar = tt >> 2, ac = (tt & 3) * 8;
    const int bk = tt >> 3, bc = (tt & 7) * 8;
    const int kbase = sub * 1024;
    float accm[4][4] = {{0.f}};

    for (int k0 = 0; k0 < 1024; k0 += 32) {
        const int kk0 = kbase + k0;
        const float4 a0 = *(const float4*)(A + (size_t)(m0 + ar) * HENC + kk0 + ac);
        const float4 a1 = *(const float4*)(A + (size_t)(m0 + ar) * HENC + kk0 + ac + 4);
        const float av[8] = {a0.x, a0.y, a0.z, a0.w, a1.x, a1.y, a1.z, a1.w};
        #pragma unroll
        for (int e = 0; e < 8; ++e) AT[sub][(ac + e) * 68 + ar] = av[e];
        *(float4*)(&Bs[sub][bk * 68 + bc])     = *(const float4*)(B + (size_t)(kk0 + bk) * EMB + n0 + bc);
        *(float4*)(&Bs[sub][bk * 68 + bc + 4]) = *(const float4*)(B + (size_t)(kk0 + bk) * EMB + n0 + bc + 4);
        __syncthreads();
        #pragma unroll 8
        for (int kk = 0; kk < 32; ++kk) {
            const float4 a = *(const float4*)(&AT[sub][kk * 68 + ti * 4]);
            const float4 b = *(const float4*)(&Bs[sub][kk * 68 + tj * 4]);
            accm[0][0] += a.x * b.x; accm[0][1] += a.x * b.y; accm[0][2] += a.x * b.z; accm[0][3] += a.x * b.w;
            accm[1][0] += a.y * b.x; accm[1][1] += a.y * b.y; accm[1][2] += a.y * b.z; accm[1][3] += a.y * b.w;
            accm[2][0] += a.z * b.x; accm[2][1] += a.z * b.y; accm[2][2] += a.z * b.z; accm[2][3] += a.z * b.w;
            accm[3][0] += a.w * b.x; accm[3][1] += a.w * b.y; accm[3][2] += a.w * b.z; accm[3][3] += a.w * b.w;
        }
        __syncthreads();
    }

    if (sub == 1) {
        #pragma unroll
        for (int i = 0; i < 4; ++i)
            #pragma unroll
            for (int j = 0; j < 4; ++j)
                red[(ti * 4 + i) * 64 + tj * 4 + j] = accm[i][j];
    }
    __syncthreads();
    if (sub == 0) {
        #pragma unroll
        for (int i = 0; i < 4; ++i) {
            const int row = m0 + ti * 4 + i;
            #pragma unroll
            for (int j = 0; j < 4; ++j) {
                const int colj = n0 + tj * 4 + j;
                const float v = (accm[i][j] + red[(ti * 4 + i) * 64 + tj * 4 + j]) + bias[colj];
                C[(size_t)row * EMB + colj] = v;
            }
        }
    }
}

// ---------------- row norms per branch ----------------
__global__ void k_sn(const float* __restrict__ latent, float* __restrict__ sn) {
    const int idx = blockIdx.x * blockDim.x + threadIdx.x;
    if (idx >= 1024) return;
    const int br = idx >> 9, r = idx & 511;
    const float* p = latent + (size_t)r * EMB + br * BR;
    float s = 0.f;
    for (int c = 0; c < BR; ++c) s += p[c] * p[c];
    sn[br * 512 + r] = s;
}

// ---------------- full distance matrix (Gram formula, as reference MST path) ----------------
__global__ __launch_bounds__(256) void k_dist(const float* __restrict__ latent,
                                              const float* __restrict__ sn,
                                              float* __restrict__ D)
{
    const int branch = blockIdx.y;
    const int ti = blockIdx.x >> 3, tj = blockIdx.x & 7;
    const int i0 = ti * 64, j0 = tj * 64;
    __shared__ float LiT[64 * 65];
    __shared__ float LjT[64 * 65];
    const int t = threadIdx.x;
    const int pi = t >> 4, pj = t & 15;
    float dot[4][4] = {{0.f}};

    for (int kc = 0; kc < BR; kc += 64) {
        for (int idx = t; idx < 1024; idx += 256) {
            const int r = idx >> 4, kq = (idx & 15) * 4;
            const float4 vi = *(const float4*)(latent + (size_t)(i0 + r) * EMB + branch * BR + kc + kq);
            const float4 vj = *(const float4*)(latent + (size_t)(j0 + r) * EMB + branch * BR + kc + kq);
            LiT[(kq + 0) * 65 + r] = vi.x; LiT[(kq + 1) * 65 + r] = vi.y;
            LiT[(kq + 2) * 65 + r] = vi.z; LiT[(kq + 3) * 65 + r] = vi.w;
            LjT[(kq + 0) * 65 + r] = vj.x; LjT[(kq + 1) * 65 + r] = vj.y;
            LjT[(kq + 2) * 65 + r] = vj.z; LjT[(kq + 3) * 65 + r] = vj.w;
        }
        __syncthreads();
        for (int k = 0; k < 64; ++k) {
            float a[4], b[4];
            #pragma unroll
            for (int i = 0; i < 4; ++i) a[i] = LiT[k * 65 + pi * 4 + i];
            #pragma unroll
            for (int j = 0; j < 4; ++j) b[j] = LjT[k * 65 + pj * 4 + j];
            #pragma unroll
            for (int i = 0; i < 4; ++i)
                #pragma unroll
                for (int j = 0; j < 4; ++j) dot[i][j] += a[i] * b[j];
        }
        __syncthreads();
    }

    const float* snb = sn + branch * 512;
    float* Db = D + (size_t)branch * 512 * 512;
    #pragma unroll
    for (int i = 0; i < 4; ++i) {
        const int gi = i0 + pi * 4 + i;
        #pragma unroll
        for (int j = 0; j < 4; ++j) {
            const int gj = j0 + pj * 4 + j;
            const float d2 = snb[gi] + snb[gj] - 2.0f * dot[i][j];
            Db[(size_t)gi * 512 + gj] = sqrtf(fmaxf(d2, 0.0f));
        }
    }
}

// ---------------- Prim's MST: 1 wave per branch + L2 prewarm; emits {mst, band} ----------------
// v3 serial chain: value-only fmin tree + single DPP wavemin + ballot/ffs scalar argmin.
// Any argmin tie-break is a valid Prim step; all MSTs share the same edge-weight multiset,
// and k_loss consumes mstb as an unordered band set -> index order is semantically free.
__global__ __launch_bounds__(256) void k_prim(const float* __restrict__ D,
                                              float2* __restrict__ mstb,
                                              float* __restrict__ acc)
{
    const int branch = blockIdx.x;
    const float* Db = D + (size_t)branch * 512 * 512;
    float2* mb = mstb + branch * 511;
    const int t = threadIdx.x;

    float s = 0.f;
    for (int i = t; i < 16384; i += 256) s += Db[(size_t)i * 16];
    if (s == -1e30f) acc[3] = s;  // never true; keeps prewarm loads alive
    __syncthreads();
    if (t >= 64) return;

    const int l = t;
    const int l8 = l << 3;
    float mind[8];
    {
        const float4* rp = (const float4*)(Db + l8);
        float4 a = rp[0], b = rp[1];
        mind[0]=a.x; mind[1]=a.y; mind[2]=a.z; mind[3]=a.w;
        mind[4]=b.x; mind[5]=b.y; mind[6]=b.z; mind[7]=b.w;
    }
    unsigned int intree = (l == 0) ? 1u : 0u;

    for (int it = 0; it < 511; ++it) {
        // masked per-lane values
        float v[8];
        #pragma unroll
        for (int e = 0; e < 8; ++e)
            v[e] = ((intree >> e) & 1u) ? 3.0e38f : mind[e];
        // value-only min tree (no index selects)
        const float m01 = fminf(v[0], v[1]), m23 = fminf(v[2], v[3]);
        const float m45 = fminf(v[4], v[5]), m67 = fminf(v[6], v[7]);
        const float best = fminf(fminf(m01, m23), fminf(m45, m67));
        // global min via single DPP chain -> lane 63 -> SGPR broadcast
        const float gred = wavemin_f(best);
        const float g = __builtin_bit_cast(float,
            __builtin_amdgcn_readlane(__builtin_bit_cast(int, gred), 63));
        // locate ANY (lane, elem) attaining g: 8 independent ballots + scalar scan
        unsigned long long eq[8];
        #pragma unroll
        for (int e = 0; e < 8; ++e) eq[e] = __ballot(v[e] == g);
        int jg = 0;
        #pragma unroll
        for (int e = 7; e >= 0; --e)
            if (eq[e]) jg = ((__ffsll((long long)eq[e]) - 1) << 3) + e;
        jg = __builtin_amdgcn_readfirstlane(jg);

        // issue row load ASAP (SGPR row base + per-lane l8 offset)
        const float* rowp = Db + ((size_t)(unsigned)jg << 9);
        const float4 u0 = *(const float4*)(rowp + l8);
        const float4 u1 = *(const float4*)(rowp + l8 + 4);

        // bookkeeping in the load shadow
        if (l == 0) mb[it] = make_float2(g, ATOLC + RTOL * fabsf(g));
        if (l == (jg >> 3)) intree |= (1u << (jg & 7));

        mind[0] = fminf(mind[0], u0.x); mind[1] = fminf(mind[1], u0.y);
        mind[2] = fminf(mind[2], u0.z); mind[3] = fminf(mind[3], u0.w);
        mind[4] = fminf(mind[4], u1.x); mind[5] = fminf(mind[5], u1.y);
        mind[6] = fminf(mind[6], u1.z); mind[7] = fminf(mind[7], u1.w);
    }
}

// ---------------- loss: pdist (diff formula) + band scan + |ETA - d| ----------------
__global__ __launch_bounds__(256) void k_loss(const float* __restrict__ latent,
                                              const float2* __restrict__ mstb,
                                              float* __restrict__ acc)
{
    const int branch = blockIdx.y;
    int bid = blockIdx.x, ti = 0;
    while (bid >= 8 - ti) { bid -= 8 - ti; ti++; }
    const int tj = ti + bid;
    const int i0 = ti * 64, j0 = tj * 64;
    __shared__ float LiT[64 * 65];
    __shared__ float LjT[64 * 65];
    const int t = threadIdx.x;
    const int pi = t >> 4, pj = t & 15;
    float d2[16];
    #pragma unroll
    for (int p = 0; p < 16; ++p) d2[p] = 0.f;

    for (int kc = 0; kc < BR; kc += 64) {
        for (int idx = t; idx < 1024; idx += 256) {
            const int r = idx >> 4, kq = (idx & 15) * 4;
            const float4 vi = *(const float4*)(latent + (size_t)(i0 + r) * EMB + branch * BR + kc + kq);
            const float4 vj = *(const float4*)(latent + (size_t)(j0 + r) * EMB + branch * BR + kc + kq);
            LiT[(kq + 0) * 65 + r] = vi.x; LiT[(kq + 1) * 65 + r] = vi.y;
            LiT[(kq + 2) * 65 + r] = vi.z; LiT[(kq + 3) * 65 + r] = vi.w;
            LjT[(kq + 0) * 65 + r] = vj.x; LjT[(kq + 1) * 65 + r] = vj.y;
            LjT[(kq + 2) * 65 + r] = vj.z; LjT[(kq + 3) * 65 + r] = vj.w;
        }
        __syncthreads();
        for (int k = 0; k < 64; ++k) {
            float a[4], b[4];
            #pragma unroll
            for (int i = 0; i < 4; ++i) a[i] = LiT[k * 65 + pi * 4 + i];
            #pragma unroll
            for (int j = 0; j < 4; ++j) b[j] = LjT[k * 65 + pj * 4 + j];
            #pragma unroll
            for (int i = 0; i < 4; ++i)
                #pragma unroll
                for (int j = 0; j < 4; ++j) {
                    const float df = a[i] - b[j];
                    d2[i * 4 + j] += df * df;
                }
        }
        __syncthreads();
    }

    float dd[16]; int valid[16];
    #pragma unroll
    for (int i = 0; i < 4; ++i)
        #pragma unroll
        for (int j = 0; j < 4; ++j) {
            const int gi = i0 + pi * 4 + i, gj = j0 + pj * 4 + j;
            dd[i * 4 + j] = sqrtf(d2[i * 4 + j]);
            valid[i * 4 + j] = (gi < gj);
        }
    const float2* mbp = mstb + branch * 511;
    unsigned int mm = 0;
    for (int m = 0; m < 511; ++m) {
        const float2 mv = mbp[m];
        #pragma unroll
        for (int p = 0; p < 16; ++p)
            if (fabsf(dd[p] - mv.x) <= mv.y) mm |= (1u << p);
    }
    float sloc = 0.f;
    #pragma unroll
    for (int p = 0; p < 16; ++p)
        if (valid[p] && ((mm >> p) & 1u)) sloc += fabsf(ETA - dd[p]);
    #pragma unroll
    for (int off = 32; off; off >>= 1) sloc += __shfl_xor(sloc, off);
    if ((t & 63) == 0) atomicAdd(&acc[1], sloc);
}

__global__ void k_final(const float* __restrict__ acc, float* __restrict__ out) {
    if (threadIdx.x == 0) {
        out[0] = acc[0] / (float)((size_t)NPTS * DIN) + acc[1];
    }
}

extern "C" void kernel_launch(void* const* d_in, const int* in_sizes, int n_in,
                              void* d_out, int out_size, void* d_ws, size_t ws_size,
                              hipStream_t stream) {
    (void)in_sizes; (void)n_in; (void)out_size; (void)ws_size;
    const float* x   = (const float*)d_in[0];
    const float* We1 = (const float*)d_in[1];
    const float* be1 = (const float*)d_in[2];
    const float* We2 = (const float*)d_in[3];
    const float* be2 = (const float*)d_in[4];
    const float* Wd1 = (const float*)d_in[5];
    const float* bd1 = (const float*)d_in[6];
    const float* Wd2 = (const float*)d_in[7];
    const float* bd2 = (const float*)d_in[8];

    // ws layout (4.73 MB peak, aliasing):
    //   acc @0, sn @4096, mstb @8192, latent @16384 (512 KB)
    //   h1 @540672 (4 MB, dead after GEMM2) / Dm aliases (dead after prim) / h2b bf16 (2 MB)
    char* ws = (char*)d_ws;
    float*          acc    = (float*)(ws);
    float*          sn     = (float*)(ws + 4096);
    float2*         mstb   = (float2*)(ws + 8192);
    float*          latent = (float*)(ws + 16384);
    float*          h1     = (float*)(ws + 540672);
    float*          Dm     = (float*)(ws + 540672);
    unsigned short* h2b    = (unsigned short*)(ws + 540672);

    k_init<<<1, 64, 0, stream>>>(acc);
    // encoder: GEMM1 via MFMA, 512-thread in-block K-split + prefetch-2
    k_mfma<0, 0, 1><<<dim3(HENC / 64, NPTS / 64), 512, 0, stream>>>(x, We1, be1, h1, nullptr, nullptr, nullptr, HENC, DIN);
    k_gemm2<<<dim3(EMB / 64, NPTS / 64), 512, 0, stream>>>(h1, We2, be2, latent);
    // connectivity loss (h1 dead; Dm aliases it)
    k_sn<<<4, 256, 0, stream>>>(latent, sn);
    k_dist<<<dim3(64, 2), 256, 0, stream>>>(latent, sn, Dm);
    k_prim<<<2, 256, 0, stream>>>(Dm, mstb, acc);
    k_loss<<<dim3(36, 2), 256, 0, stream>>>(latent, mstb, acc);
    // decoder: GEMM3 (K=256, latency-bound -> K-split) + GEMM4 fused MSE
    k_mfma<1, 0, 1><<<dim3(HDEC / 64, NPTS / 64), 512, 0, stream>>>(latent, Wd1, bd1, nullptr, h2b, nullptr, nullptr, HDEC, EMB);
    k_mfma<2, 1, 0><<<dim3(DIN / 64, NPTS / 64), 256, 0, stream>>>(h2b, Wd2, bd2, nullptr, nullptr, x, acc, DIN, HDEC);
    k_final<<<1, 64, 0, stream>>>(acc, (float*)d_out);
}

// Round 4
// 715.215 us; speedup vs baseline: 1.2496x; 1.2496x over previous
//
#include <hip/hip_runtime.h>
#include <stdint.h>

#define NPTS 512
#define DIN  8192
#define HENC 2048
#define EMB  256
#define HDEC 2048
#define BR   128
#define ETA  2.0f
#define RTOL 1e-4f
#define ATOLC 1e-8f

typedef __attribute__((ext_vector_type(8))) short bf16x8;
typedef __attribute__((ext_vector_type(4))) float f32x4;
typedef __attribute__((ext_vector_type(8))) unsigned short u16x8;

__device__ __forceinline__ unsigned short f2bf(float f) {
    unsigned int x = __builtin_bit_cast(unsigned int, f);
    unsigned int lsb = (x >> 16) & 1u;
    x += 0x7fffu + lsb;
    return (unsigned short)(x >> 16);
}

// DPP-based wave64 min-reduce (VALU-latency cross-lane; result valid in lane 63).
template<int CTRL>
__device__ __forceinline__ float dppmin_f(float x) {
    int xi = __builtin_bit_cast(int, x);
    int f = __builtin_amdgcn_update_dpp(xi, xi, CTRL, 0xf, 0xf, false);
    return fminf(x, __builtin_bit_cast(float, f));
}
__device__ __forceinline__ float wavemin_f(float x) {
    x = dppmin_f<0x111>(x);  // row_shr:1
    x = dppmin_f<0x112>(x);  // row_shr:2
    x = dppmin_f<0x114>(x);  // row_shr:4
    x = dppmin_f<0x118>(x);  // row_shr:8
    x = dppmin_f<0x142>(x);  // row_bcast:15
    x = dppmin_f<0x143>(x);  // row_bcast:31
    return x;
}

__global__ void k_init(float* acc) {
    if (threadIdx.x < 4) acc[threadIdx.x] = 0.0f;
}

// ============ bf16 MFMA GEMM v3: 64x64 tile, BK=32, LDS dbuf, prefetch-2, optional K-split ============
// OUT==0: Cf = relu(A@B+bias) f32   (GEMM1: h1)
// OUT==1: Cb = bf16(relu(A@B+bias)) (GEMM3: h2b)
// OUT==2: acc += sum((X-(A@B+bias))^2) (GEMM4, recon never stored)
// A_BF16==1: A is bf16 ushort; else f32 converted in staging.
// SPLIT==1: 512 threads, two 256-thread halves each do K/2 with own LDS dbuf, LDS-reduce at end.
template<int OUT, int A_BF16, int SPLIT>
__global__ __launch_bounds__(SPLIT ? 512 : 256) void k_mfma(
    const void* __restrict__ Araw,
    const float* __restrict__ B,
    const float* __restrict__ bias,
    float* __restrict__ Cf,
    unsigned short* __restrict__ Cb,
    const float* __restrict__ X,
    float* __restrict__ acc,
    int Nn, int K)
{
    __shared__ unsigned short As[SPLIT ? 2 : 1][2][64 * 40];  // [sub][buf][m*40+k]
    __shared__ unsigned int   Bd[SPLIT ? 2 : 1][2][64 * 20];  // [sub][buf][n*20+kd]
    __shared__ float          red[SPLIT ? 4096 : 1];
    const int t = threadIdx.x;
    const int sub = SPLIT ? (t >> 8) : 0;
    const int tt = SPLIT ? (t & 255) : t;
    const int w = tt >> 6;
    const int l = tt & 63;
    const int quad = l >> 4;
    const int r16 = l & 15;
    const int n0 = blockIdx.x * 64;
    const int m0 = blockIdx.y * 64;

    const int ar = tt >> 2, ac = (tt & 3) * 8;     // A staging
    const int kp = tt & 15, n4 = (tt >> 4) * 4;    // B staging

    const int kb = sub * (K >> SPLIT);
    const int ke = kb + (K >> SPLIT);

    f32x4 c0 = {0,0,0,0}, c1 = {0,0,0,0}, c2 = {0,0,0,0}, c3 = {0,0,0,0};

    int4   aI_0, aI_1;
    float4 aF0_0, aF1_0, bR0_0, bR1_0;
    float4 aF0_1, aF1_1, bR0_1, bR1_1;

    #define LOAD_T(S, k0)                                                              \
        do {                                                                           \
            if (A_BF16) {                                                              \
                const unsigned short* A = (const unsigned short*)Araw;                 \
                aI_##S = *(const int4*)(A + (size_t)(m0 + ar) * K + (k0) + ac);        \
            } else {                                                                   \
                const float* A = (const float*)Araw;                                   \
                aF0_##S = *(const float4*)(A + (size_t)(m0 + ar) * K + (k0) + ac);     \
                aF1_##S = *(const float4*)(A + (size_t)(m0 + ar) * K + (k0) + ac + 4); \
            }                                                                          \
            bR0_##S = *(const float4*)(B + (size_t)((k0) + 2 * kp) * Nn + n0 + n4);    \
            bR1_##S = *(const float4*)(B + (size_t)((k0) + 2 * kp + 1) * Nn + n0 + n4);\
        } while (0)

    #define STORE_T(S, buf)                                                            \
        do {                                                                           \
            if (A_BF16) {                                                              \
                *(int4*)(&As[sub][buf][ar * 40 + ac]) = aI_##S;                        \
            } else {                                                                   \
                int4 p;                                                                \
                p.x = (int)(((unsigned)f2bf(aF0_##S.y) << 16) | f2bf(aF0_##S.x));      \
                p.y = (int)(((unsigned)f2bf(aF0_##S.w) << 16) | f2bf(aF0_##S.z));      \
                p.z = (int)(((unsigned)f2bf(aF1_##S.y) << 16) | f2bf(aF1_##S.x));      \
                p.w = (int)(((unsigned)f2bf(aF1_##S.w) << 16) | f2bf(aF1_##S.z));      \
                *(int4*)(&As[sub][buf][ar * 40 + ac]) = p;                             \
            }                                                                          \
            const float bl[4] = {bR0_##S.x, bR0_##S.y, bR0_##S.z, bR0_##S.w};          \
            const float bh[4] = {bR1_##S.x, bR1_##S.y, bR1_##S.z, bR1_##S.w};          \
            _Pragma("unroll")                                                          \
            for (int i = 0; i < 4; ++i)                                                \
                Bd[sub][buf][(n4 + i) * 20 + kp] =                                     \
                    ((unsigned)f2bf(bh[i]) << 16) | f2bf(bl[i]);                       \
        } while (0)

    #define COMP(buf)                                                                  \
        do {                                                                           \
            bf16x8 bf = *(const bf16x8*)(&Bd[sub][buf][(w * 16 + r16) * 20 + quad * 4]);\
            bf16x8 a0 = *(const bf16x8*)(&As[sub][buf][(0  + r16) * 40 + quad * 8]);   \
            bf16x8 a1 = *(const bf16x8*)(&As[sub][buf][(16 + r16) * 40 + quad * 8]);   \
            bf16x8 a2 = *(const bf16x8*)(&As[sub][buf][(32 + r16) * 40 + quad * 8]);   \
            bf16x8 a3 = *(const bf16x8*)(&As[sub][buf][(48 + r16) * 40 + quad * 8]);   \
            c0 = __builtin_amdgcn_mfma_f32_16x16x32_bf16(a0, bf, c0, 0, 0, 0);         \
            c1 = __builtin_amdgcn_mfma_f32_16x16x32_bf16(a1, bf, c1, 0, 0, 0);         \
            c2 = __builtin_amdgcn_mfma_f32_16x16x32_bf16(a2, bf, c2, 0, 0, 0);         \
            c3 = __builtin_amdgcn_mfma_f32_16x16x32_bf16(a3, bf, c3, 0, 0, 0);         \
        } while (0)

    // prologue: tiles kb, kb+32 in flight; tile kb staged to buf0
    LOAD_T(0, kb);
    LOAD_T(1, kb + 32);
    STORE_T(0, 0);
    int cur = 0;
    // main loop: two tiles per trip, one barrier per tile
    for (int k0 = kb; k0 < ke; k0 += 64) {
        if (k0 + 64 < ke) LOAD_T(0, k0 + 64);
        __syncthreads();            // buf[cur] (tile k0) ready; prior reads of buf[cur^1] done
        COMP(cur);
        STORE_T(1, cur ^ 1);        // tile k0+32 (loads issued one tile ago)
        cur ^= 1;
        if (k0 + 96 < ke) LOAD_T(1, k0 + 96);
        __syncthreads();            // buf[cur] (tile k0+32) ready
        COMP(cur);
        if (k0 + 64 < ke) { STORE_T(0, cur ^ 1); cur ^= 1; }
    }
    #undef LOAD_T
    #undef STORE_T
    #undef COMP

    f32x4 frags[4] = {c0, c1, c2, c3};

    if (SPLIT) {
        if (sub == 1) {
            #pragma unroll
            for (int f = 0; f < 4; ++f)
                #pragma unroll
                for (int rg = 0; rg < 4; ++rg)
                    red[(f * 16 + quad * 4 + rg) * 64 + w * 16 + r16] = frags[f][rg];
        }
        __syncthreads();
        if (sub == 1) return;
        #pragma unroll
        for (int f = 0; f < 4; ++f)
            #pragma unroll
            for (int rg = 0; rg < 4; ++rg)
                frags[f][rg] += red[(f * 16 + quad * 4 + rg) * 64 + w * 16 + r16];
    }

    const int col = n0 + w * 16 + r16;
    const float bval = bias[col];
    float local = 0.f;
    #pragma unroll
    for (int f = 0; f < 4; ++f) {
        #pragma unroll
        for (int rg = 0; rg < 4; ++rg) {
            const int row = m0 + f * 16 + quad * 4 + rg;  // C/D: col=lane&15, row=quad*4+reg (m89)
            const float v = frags[f][rg] + bval;
            if (OUT == 0) {
                Cf[(size_t)row * Nn + col] = fmaxf(v, 0.f);
            } else if (OUT == 1) {
                Cb[(size_t)row * Nn + col] = f2bf(fmaxf(v, 0.f));
            } else {
                const float d = X[(size_t)row * Nn + col] - v;
                local += d * d;
            }
        }
    }
    if (OUT == 2) {
        #pragma unroll
        for (int off = 32; off; off >>= 1) local += __shfl_xor(local, off);
        if (l == 0) atomicAdd(acc, local);
    }
}

// ============ GEMM2 (latent = h1@We2+b2), fp32 VALU, 64x64 tile, in-block 2-way K-split ============
__global__ __launch_bounds__(512) void k_gemm2(
    const float* __restrict__ A,     // [512,2048]
    const float* __restrict__ B,     // [2048,256]
    const float* __restrict__ bias,  // [256]
    float* __restrict__ C)           // [512,256]
{
    __shared__ float AT[2][32 * 68];
    __shared__ float Bs[2][32 * 68];
    __shared__ float red[64 * 64];
    const int t = threadIdx.x;
    const int sub = t >> 8, tt = t & 255;
    const int m0 = blockIdx.y * 64, n0 = blockIdx.x * 64;
    const int ti = tt >> 4, tj = tt & 15;
    const int ar = tt >> 2, ac = (tt & 3) * 8;
    const int bk = tt >> 3, bc = (tt & 7) * 8;
    const int kbase = sub * 1024;
    float accm[4][4] = {{0.f}};

    for (int k0 = 0; k0 < 1024; k0 += 32) {
        const int kk0 = kbase + k0;
        const float4 a0 = *(const float4*)(A + (size_t)(m0 + ar) * HENC + kk0 + ac);
        const float4 a1 = *(const float4*)(A + (size_t)(m0 + ar) * HENC + kk0 + ac + 4);
        const float av[8] = {a0.x, a0.y, a0.z, a0.w, a1.x, a1.y, a1.z, a1.w};
        #pragma unroll
        for (int e = 0; e < 8; ++e) AT[sub][(ac + e) * 68 + ar] = av[e];
        *(float4*)(&Bs[sub][bk * 68 + bc])     = *(const float4*)(B + (size_t)(kk0 + bk) * EMB + n0 + bc);
        *(float4*)(&Bs[sub][bk * 68 + bc + 4]) = *(const float4*)(B + (size_t)(kk0 + bk) * EMB + n0 + bc + 4);
        __syncthreads();
        #pragma unroll 8
        for (int kk = 0; kk < 32; ++kk) {
            const float4 a = *(const float4*)(&AT[sub][kk * 68 + ti * 4]);
            const float4 b = *(const float4*)(&Bs[sub][kk * 68 + tj * 4]);
            accm[0][0] += a.x * b.x; accm[0][1] += a.x * b.y; accm[0][2] += a.x * b.z; accm[0][3] += a.x * b.w;
            accm[1][0] += a.y * b.x; accm[1][1] += a.y * b.y; accm[1][2] += a.y * b.z; accm[1][3] += a.y * b.w;
            accm[2][0] += a.z * b.x; accm[2][1] += a.z * b.y; accm[2][2] += a.z * b.z; accm[2][3] += a.z * b.w;
            accm[3][0] += a.w * b.x; accm[3][1] += a.w * b.y; accm[3][2] += a.w * b.z; accm[3][3] += a.w * b.w;
        }
        __syncthreads();
    }

    if (sub == 1) {
        #pragma unroll
        for (int i = 0; i < 4; ++i)
            #pragma unroll
            for (int j = 0; j < 4; ++j)
                red[(ti * 4 + i) * 64 + tj * 4 + j] = accm[i][j];
    }
    __syncthreads();
    if (sub == 0) {
        #pragma unroll
        for (int i = 0; i < 4; ++i) {
            const int row = m0 + ti * 4 + i;
            #pragma unroll
            for (int j = 0; j < 4; ++j) {
                const int colj = n0 + tj * 4 + j;
                const float v = (accm[i][j] + red[(ti * 4 + i) * 64 + tj * 4 + j]) + bias[colj];
                C[(size_t)row * EMB + colj] = v;
            }
        }
    }
}

// ---------------- row norms per branch ----------------
__global__ void k_sn(const float* __restrict__ latent, float* __restrict__ sn) {
    const int idx = blockIdx.x * blockDim.x + threadIdx.x;
    if (idx >= 1024) return;
    const int br = idx >> 9, r = idx & 511;
    const float* p = latent + (size_t)r * EMB + br * BR;
    float s = 0.f;
    for (int c = 0; c < BR; ++c) s += p[c] * p[c];
    sn[br * 512 + r] = s;
}

// ---------------- full distance matrix (Gram formula, as reference MST path) ----------------
__global__ __launch_bounds__(256) void k_dist(const float* __restrict__ latent,
                                              const float* __restrict__ sn,
                                              float* __restrict__ D)
{
    const int branch = blockIdx.y;
    const int ti = blockIdx.x >> 3, tj = blockIdx.x & 7;
    const int i0 = ti * 64, j0 = tj * 64;
    __shared__ float LiT[64 * 65];
    __shared__ float LjT[64 * 65];
    const int t = threadIdx.x;
    const int pi = t >> 4, pj = t & 15;
    float dot[4][4] = {{0.f}};

    for (int kc = 0; kc < BR; kc += 64) {
        for (int idx = t; idx < 1024; idx += 256) {
            const int r = idx >> 4, kq = (idx & 15) * 4;
            const float4 vi = *(const float4*)(latent + (size_t)(i0 + r) * EMB + branch * BR + kc + kq);
            const float4 vj = *(const float4*)(latent + (size_t)(j0 + r) * EMB + branch * BR + kc + kq);
            LiT[(kq + 0) * 65 + r] = vi.x; LiT[(kq + 1) * 65 + r] = vi.y;
            LiT[(kq + 2) * 65 + r] = vi.z; LiT[(kq + 3) * 65 + r] = vi.w;
            LjT[(kq + 0) * 65 + r] = vj.x; LjT[(kq + 1) * 65 + r] = vj.y;
            LjT[(kq + 2) * 65 + r] = vj.z; LjT[(kq + 3) * 65 + r] = vj.w;
        }
        __syncthreads();
        for (int k = 0; k < 64; ++k) {
            float a[4], b[4];
            #pragma unroll
            for (int i = 0; i < 4; ++i) a[i] = LiT[k * 65 + pi * 4 + i];
            #pragma unroll
            for (int j = 0; j < 4; ++j) b[j] = LjT[k * 65 + pj * 4 + j];
            #pragma unroll
            for (int i = 0; i < 4; ++i)
                #pragma unroll
                for (int j = 0; j < 4; ++j) dot[i][j] += a[i] * b[j];
        }
        __syncthreads();
    }

    const float* snb = sn + branch * 512;
    float* Db = D + (size_t)branch * 512 * 512;
    #pragma unroll
    for (int i = 0; i < 4; ++i) {
        const int gi = i0 + pi * 4 + i;
        #pragma unroll
        for (int j = 0; j < 4; ++j) {
            const int gj = j0 + pj * 4 + j;
            const float d2 = snb[gi] + snb[gj] - 2.0f * dot[i][j];
            Db[(size_t)gi * 512 + gj] = sqrtf(fmaxf(d2, 0.0f));
        }
    }
}

// ---------------- Boruvka MST: parallel rounds replace Prim's 511-long serial chain ----------------
// Valid because the MST is unique (random-normal data -> distinct f32 distances) and k_loss
// consumes mstb as an unordered band set. Each round: per-vertex masked argmin over its row
// (one wave per vertex, 16 waves), per-component LDS atomicMin reduce, mutual-edge dedupe,
// hooking + 9x pointer-jump. <=9 rounds of ~10k cyc vs 511 x ~1100 cyc serial.
__global__ __launch_bounds__(1024) void k_prim(const float* __restrict__ D,
                                               float2* __restrict__ mstb,
                                               float* __restrict__ acc)
{
    const int branch = blockIdx.x;
    const float* Db = D + (size_t)branch * 512 * 512;
    const int t = threadIdx.x;
    const int wid = t >> 6;      // wave id 0..15
    const int l = t & 63;
    const int l8 = l << 3;

    __shared__ unsigned short comp16[512];   // component label per vertex (a root vertex id)
    __shared__ unsigned       parent[512];   // hooking forest, per round
    __shared__ unsigned short minj[512];     // per-vertex argmin column
    __shared__ unsigned       minwb[512];    // per-vertex min weight bits (f32, positive -> u32 ordered)
    __shared__ unsigned       cminw[512];    // per-component min weight bits
    __shared__ unsigned       csrc[512];     // per-component winning vertex
    __shared__ float          elist[512];    // emitted MST edge weights
    __shared__ int            ne_sh;

    const unsigned SENT = 0x7f61b1e6u;       // bits of 3.0e38f (masked-out sentinel)

    for (int i = t; i < 512; i += 1024) comp16[i] = (unsigned short)i;
    if (t == 0) ne_sh = 0;

    // prewarm D into this XCD's L2 (1 MB, every 64B line)
    float s = 0.f;
    for (int i = t; i < 16384; i += 1024) s += Db[(size_t)i * 16];
    if (s == -1e30f) acc[3] = s;  // never true; keeps prewarm loads alive
    __syncthreads();

    int ne = 0;
    for (int round = 0; round < 12 && ne < 511; ++round) {
        for (int i = t; i < 512; i += 1024) {
            cminw[i] = 0xFFFFFFFFu;
            csrc[i]  = 0xFFFFFFFFu;
            parent[i] = (unsigned)i;
        }
        __syncthreads();

        // hoist this lane's component slice (comp16 is frozen during the scan phase)
        const u16x8 cj = *(const u16x8*)(&comp16[l8]);

        // per-vertex masked argmin over its row; one wave per vertex, vertices independent
        for (int v = wid; v < 512; v += 16) {
            const unsigned cv = comp16[v];   // uniform-address LDS broadcast
            const float4 d0 = *(const float4*)(Db + (size_t)v * 512 + l8);
            const float4 d1 = *(const float4*)(Db + (size_t)v * 512 + l8 + 4);
            const float vv[8] = {d0.x, d0.y, d0.z, d0.w, d1.x, d1.y, d1.z, d1.w};
            float best = 3.0e38f; int bi = 0;
            #pragma unroll
            for (int e = 0; e < 8; ++e) {
                const float m = ((unsigned)cj[e] == cv) ? 3.0e38f : vv[e];
                if (m < best) { best = m; bi = e; }
            }
            const float gr = wavemin_f(best);
            const unsigned gbits = (unsigned)__builtin_amdgcn_readlane(
                __builtin_bit_cast(int, gr), 63);
            const float g = __builtin_bit_cast(float, gbits);
            const unsigned long long msk = __ballot(best == g);
            const int src = __ffsll((long long)msk) - 1;
            const int jg = __builtin_amdgcn_readlane(l8 + bi, src);
            if (l == 0) {
                minwb[v] = (gbits == SENT) ? 0xFFFFFFFFu : gbits;
                minj[v]  = (unsigned short)jg;
                if (gbits != SENT) atomicMin(&cminw[cv], gbits);
            }
        }
        __syncthreads();

        // per-component winner vertex (any vertex attaining the component min)
        for (int v = t; v < 512; v += 1024) {
            const unsigned mw = minwb[v];
            if (mw != 0xFFFFFFFFu && mw == cminw[comp16[v]])
                atomicMin(&csrc[comp16[v]], (unsigned)v);
        }
        __syncthreads();

        // emit + hook per component root
        for (int c = t; c < 512; c += 1024) {
            const unsigned sv = csrc[c];
            if (sv != 0xFFFFFFFFu) {
                const unsigned wbits = cminw[c];
                const unsigned j = minj[sv];
                const unsigned c2 = comp16[j];
                const bool mutual = (cminw[c2] == wbits);  // distinct weights -> same edge
                if (!mutual || (unsigned)c < c2)
                    elist[atomicAdd(&ne_sh, 1)] = __builtin_bit_cast(float, wbits);
                parent[c] = (mutual && (unsigned)c < c2) ? (unsigned)c : c2;
            }
        }
        __syncthreads();

        // pointer jumping (chains <= 512 -> 9 doubling passes; u32 races are benign/monotone)
        for (int pj = 0; pj < 9; ++pj) {
            for (int i = t; i < 512; i += 1024) parent[i] = parent[parent[i]];
            __syncthreads();
        }
        for (int i = t; i < 512; i += 1024) comp16[i] = (unsigned short)parent[comp16[i]];
        __syncthreads();
        ne = ne_sh;
    }

    for (int i = t; i < 511; i += 1024) {
        const float w = elist[i];
        mstb[branch * 511 + i] = make_float2(w, ATOLC + RTOL * fabsf(w));
    }
}

// ---------------- loss: pdist (diff formula) + band scan + |ETA - d| ----------------
__global__ __launch_bounds__(256) void k_loss(const float* __restrict__ latent,
                                              const float2* __restrict__ mstb,
                                              float* __restrict__ acc)
{
    const int branch = blockIdx.y;
    int bid = blockIdx.x, ti = 0;
    while (bid >= 8 - ti) { bid -= 8 - ti; ti++; }
    const int tj = ti + bid;
    const int i0 = ti * 64, j0 = tj * 64;
    __shared__ float LiT[64 * 65];
    __shared__ float LjT[64 * 65];
    const int t = threadIdx.x;
    const int pi = t >> 4, pj = t & 15;
    float d2[16];
    #pragma unroll
    for (int p = 0; p < 16; ++p) d2[p] = 0.f;

    for (int kc = 0; kc < BR; kc += 64) {
        for (int idx = t; idx < 1024; idx += 256) {
            const int r = idx >> 4, kq = (idx & 15) * 4;
            const float4 vi = *(const float4*)(latent + (size_t)(i0 + r) * EMB + branch * BR + kc + kq);
            const float4 vj = *(const float4*)(latent + (size_t)(j0 + r) * EMB + branch * BR + kc + kq);
            LiT[(kq + 0) * 65 + r] = vi.x; LiT[(kq + 1) * 65 + r] = vi.y;
            LiT[(kq + 2) * 65 + r] = vi.z; LiT[(kq + 3) * 65 + r] = vi.w;
            LjT[(kq + 0) * 65 + r] = vj.x; LjT[(kq + 1) * 65 + r] = vj.y;
            LjT[(kq + 2) * 65 + r] = vj.z; LjT[(kq + 3) * 65 + r] = vj.w;
        }
        __syncthreads();
        for (int k = 0; k < 64; ++k) {
            float a[4], b[4];
            #pragma unroll
            for (int i = 0; i < 4; ++i) a[i] = LiT[k * 65 + pi * 4 + i];
            #pragma unroll
            for (int j = 0; j < 4; ++j) b[j] = LjT[k * 65 + pj * 4 + j];
            #pragma unroll
            for (int i = 0; i < 4; ++i)
                #pragma unroll
                for (int j = 0; j < 4; ++j) {
                    const float df = a[i] - b[j];
                    d2[i * 4 + j] += df * df;
                }
        }
        __syncthreads();
    }

    float dd[16]; int valid[16];
    #pragma unroll
    for (int i = 0; i < 4; ++i)
        #pragma unroll
        for (int j = 0; j < 4; ++j) {
            const int gi = i0 + pi * 4 + i, gj = j0 + pj * 4 + j;
            dd[i * 4 + j] = sqrtf(d2[i * 4 + j]);
            valid[i * 4 + j] = (gi < gj);
        }
    const float2* mbp = mstb + branch * 511;
    unsigned int mm = 0;
    for (int m = 0; m < 511; ++m) {
        const float2 mv = mbp[m];
        #pragma unroll
        for (int p = 0; p < 16; ++p)
            if (fabsf(dd[p] - mv.x) <= mv.y) mm |= (1u << p);
    }
    float sloc = 0.f;
    #pragma unroll
    for (int p = 0; p < 16; ++p)
        if (valid[p] && ((mm >> p) & 1u)) sloc += fabsf(ETA - dd[p]);
    #pragma unroll
    for (int off = 32; off; off >>= 1) sloc += __shfl_xor(sloc, off);
    if ((t & 63) == 0) atomicAdd(&acc[1], sloc);
}

__global__ void k_final(const float* __restrict__ acc, float* __restrict__ out) {
    if (threadIdx.x == 0) {
        out[0] = acc[0] / (float)((size_t)NPTS * DIN) + acc[1];
    }
}

extern "C" void kernel_launch(void* const* d_in, const int* in_sizes, int n_in,
                              void* d_out, int out_size, void* d_ws, size_t ws_size,
                              hipStream_t stream) {
    (void)in_sizes; (void)n_in; (void)out_size; (void)ws_size;
    const float* x   = (const float*)d_in[0];
    const float* We1 = (const float*)d_in[1];
    const float* be1 = (const float*)d_in[2];
    const float* We2 = (const float*)d_in[3];
    const float* be2 = (const float*)d_in[4];
    const float* Wd1 = (const float*)d_in[5];
    const float* bd1 = (const float*)d_in[6];
    const float* Wd2 = (const float*)d_in[7];
    const float* bd2 = (const float*)d_in[8];

    // ws layout (4.73 MB peak, aliasing):
    //   acc @0, sn @4096, mstb @8192, latent @16384 (512 KB)
    //   h1 @540672 (4 MB, dead after GEMM2) / Dm aliases (dead after prim) / h2b bf16 (2 MB)
    char* ws = (char*)d_ws;
    float*          acc    = (float*)(ws);
    float*          sn     = (float*)(ws + 4096);
    float2*         mstb   = (float2*)(ws + 8192);
    float*          latent = (float*)(ws + 16384);
    float*          h1     = (float*)(ws + 540672);
    float*          Dm     = (float*)(ws + 540672);
    unsigned short* h2b    = (unsigned short*)(ws + 540672);

    k_init<<<1, 64, 0, stream>>>(acc);
    // encoder: GEMM1 via MFMA, 512-thread in-block K-split + prefetch-2
    k_mfma<0, 0, 1><<<dim3(HENC / 64, NPTS / 64), 512, 0, stream>>>(x, We1, be1, h1, nullptr, nullptr, nullptr, HENC, DIN);
    k_gemm2<<<dim3(EMB / 64, NPTS / 64), 512, 0, stream>>>(h1, We2, be2, latent);
    // connectivity loss (h1 dead; Dm aliases it)
    k_sn<<<4, 256, 0, stream>>>(latent, sn);
    k_dist<<<dim3(64, 2), 256, 0, stream>>>(latent, sn, Dm);
    k_prim<<<2, 1024, 0, stream>>>(Dm, mstb, acc);
    k_loss<<<dim3(36, 2), 256, 0, stream>>>(latent, mstb, acc);
    // decoder: GEMM3 (K=256, latency-bound -> K-split) + GEMM4 fused MSE
    k_mfma<1, 0, 1><<<dim3(HDEC / 64, NPTS / 64), 512, 0, stream>>>(latent, Wd1, bd1, nullptr, h2b, nullptr, nullptr, HDEC, EMB);
    k_mfma<2, 1, 0><<<dim3(DIN / 64, NPTS / 64), 256, 0, stream>>>(h2b, Wd2, bd2, nullptr, nullptr, x, acc, DIN, HDEC);
    k_final<<<1, 64, 0, stream>>>(acc, (float*)d_out);
}

// Round 5
// 628.598 us; speedup vs baseline: 1.4217x; 1.1378x over previous
//
#include <hip/hip_runtime.h>
#include <stdint.h>

#define NPTS 512
#define DIN  8192
#define HENC 2048
#define EMB  256
#define HDEC 2048
#define BR   128
#define ETA  2.0f
#define RTOL 1e-4f
#define ATOLC 1e-8f

typedef __attribute__((ext_vector_type(8))) short bf16x8;
typedef __attribute__((ext_vector_type(4))) float f32x4;
typedef __attribute__((ext_vector_type(8))) unsigned short u16x8;

__device__ __forceinline__ unsigned short f2bf(float f) {
    unsigned int x = __builtin_bit_cast(unsigned int, f);
    unsigned int lsb = (x >> 16) & 1u;
    x += 0x7fffu + lsb;
    return (unsigned short)(x >> 16);
}

// packed f32x2 -> bf16x2 (RNE, matches f2bf bitwise): D[15:0]=bf16(lo), D[31:16]=bf16(hi)
__device__ __forceinline__ unsigned cvtpk(float lo, float hi) {
    unsigned d;
    asm("v_cvt_pk_bf16_f32 %0, %1, %2" : "=v"(d) : "v"(lo), "v"(hi));
    return d;
}

// DPP-based wave64 min-reduce (VALU-latency cross-lane; result valid in lane 63).
template<int CTRL>
__device__ __forceinline__ float dppmin_f(float x) {
    int xi = __builtin_bit_cast(int, x);
    int f = __builtin_amdgcn_update_dpp(xi, xi, CTRL, 0xf, 0xf, false);
    return fminf(x, __builtin_bit_cast(float, f));
}
__device__ __forceinline__ float wavemin_f(float x) {
    x = dppmin_f<0x111>(x);  // row_shr:1
    x = dppmin_f<0x112>(x);  // row_shr:2
    x = dppmin_f<0x114>(x);  // row_shr:4
    x = dppmin_f<0x118>(x);  // row_shr:8
    x = dppmin_f<0x142>(x);  // row_bcast:15
    x = dppmin_f<0x143>(x);  // row_bcast:31
    return x;
}

__global__ void k_init(float* acc) {
    if (threadIdx.x < 4) acc[threadIdx.x] = 0.0f;
}

// ---------------- pre-convert passes (run once; halve GEMM operand bytes) ----------------
// x f32 -> bf16 row-major (same layout)
__global__ __launch_bounds__(256) void k_cvt(const float* __restrict__ in,
                                             unsigned* __restrict__ out)
{
    const size_t id = (size_t)blockIdx.x * 256 + threadIdx.x;   // one int4 = 8 floats
    const float4 a = *(const float4*)(in + id * 8);
    const float4 b = *(const float4*)(in + id * 8 + 4);
    int4 o;
    o.x = (int)cvtpk(a.x, a.y); o.y = (int)cvtpk(a.z, a.w);
    o.z = (int)cvtpk(b.x, b.y); o.w = (int)cvtpk(b.z, b.w);
    *(int4*)(out + id * 4) = o;
}

// B [K][N] f32 -> [K/2][N] u32, dword = bf16(B[2kd][n]) | bf16(B[2kd+1][n])<<16
// (exactly the Bd LDS dword format -> GEMM B staging becomes pure copy)
__global__ __launch_bounds__(256) void k_pack(const float* __restrict__ in,
                                              unsigned* __restrict__ out, int N)
{
    const int id = blockIdx.x * 256 + threadIdx.x;   // one int4 = 4 output dwords
    const int perRow = N >> 2;
    const int row = id / perRow;          // kd
    const int col = (id - row * perRow) << 2;
    const float4 r0 = *(const float4*)(in + (size_t)(2 * row) * N + col);
    const float4 r1 = *(const float4*)(in + (size_t)(2 * row + 1) * N + col);
    int4 o;
    o.x = (int)cvtpk(r0.x, r1.x); o.y = (int)cvtpk(r0.y, r1.y);
    o.z = (int)cvtpk(r0.z, r1.z); o.w = (int)cvtpk(r0.w, r1.w);
    *(int4*)(out + (size_t)row * N + col) = o;
}

// ============ bf16 MFMA GEMM: 64x64 tile, BK=32, LDS dbuf, prefetch-2, optional K-split ============
// OUT==0: Cf = relu(A@B+bias) f32   (GEMM1: h1)
// OUT==1: Cb = bf16(relu(A@B+bias)) (GEMM3: h2b)
// OUT==2: acc += sum((X-(A@B+bias))^2) (GEMM4, recon never stored)
// A_BF16==1: A is bf16 ushort; else f32 converted in staging (cvt_pk).
// BPK==1: B is pre-packed u32 [K/2][N] (k-pair dwords) -> staging is pure copy.
// SPLIT==1: 512 threads, two 256-thread halves each do K/2 with own LDS dbuf, LDS-reduce at end.
template<int OUT, int A_BF16, int SPLIT, int BPK>
__global__ __launch_bounds__(SPLIT ? 512 : 256) void k_mfma(
    const void* __restrict__ Araw,
    const void* __restrict__ Braw,
    const float* __restrict__ bias,
    float* __restrict__ Cf,
    unsigned short* __restrict__ Cb,
    const float* __restrict__ X,
    float* __restrict__ acc,
    int Nn, int K)
{
    __shared__ unsigned short As[SPLIT ? 2 : 1][2][64 * 40];  // [sub][buf][m*40+k]
    __shared__ unsigned int   Bd[SPLIT ? 2 : 1][2][64 * 20];  // [sub][buf][n*20+kd]
    __shared__ float          red[SPLIT ? 4096 : 1];
    const int t = threadIdx.x;
    const int sub = SPLIT ? (t >> 8) : 0;
    const int tt = SPLIT ? (t & 255) : t;
    const int w = tt >> 6;
    const int l = tt & 63;
    const int quad = l >> 4;
    const int r16 = l & 15;
    const int n0 = blockIdx.x * 64;
    const int m0 = blockIdx.y * 64;

    const int ar = tt >> 2, ac = (tt & 3) * 8;     // A staging
    const int kp = tt & 15, n4 = (tt >> 4) * 4;    // B staging

    const int kb = sub * (K >> SPLIT);
    const int ke = kb + (K >> SPLIT);

    f32x4 c0 = {0,0,0,0}, c1 = {0,0,0,0}, c2 = {0,0,0,0}, c3 = {0,0,0,0};

    int4   aI_0, aI_1, bP_0, bP_1;
    float4 aF0_0, aF1_0, bR0_0, bR1_0;
    float4 aF0_1, aF1_1, bR0_1, bR1_1;

    #define LOAD_T(S, k0)                                                              \
        do {                                                                           \
            if (A_BF16) {                                                              \
                const unsigned short* A = (const unsigned short*)Araw;                 \
                aI_##S = *(const int4*)(A + (size_t)(m0 + ar) * K + (k0) + ac);        \
            } else {                                                                   \
                const float* A = (const float*)Araw;                                   \
                aF0_##S = *(const float4*)(A + (size_t)(m0 + ar) * K + (k0) + ac);     \
                aF1_##S = *(const float4*)(A + (size_t)(m0 + ar) * K + (k0) + ac + 4); \
            }                                                                          \
            if (BPK) {                                                                 \
                const unsigned* Bp = (const unsigned*)Braw;                            \
                bP_##S = *(const int4*)(Bp + (size_t)(((k0) >> 1) + kp) * Nn + n0 + n4);\
            } else {                                                                   \
                const float* B = (const float*)Braw;                                   \
                bR0_##S = *(const float4*)(B + (size_t)((k0) + 2 * kp) * Nn + n0 + n4);\
                bR1_##S = *(const float4*)(B + (size_t)((k0) + 2 * kp + 1) * Nn + n0 + n4);\
            }                                                                          \
        } while (0)

    #define STORE_T(S, buf)                                                            \
        do {                                                                           \
            if (A_BF16) {                                                              \
                *(int4*)(&As[sub][buf][ar * 40 + ac]) = aI_##S;                        \
            } else {                                                                   \
                int4 p;                                                                \
                p.x = (int)cvtpk(aF0_##S.x, aF0_##S.y);                                \
                p.y = (int)cvtpk(aF0_##S.z, aF0_##S.w);                                \
                p.z = (int)cvtpk(aF1_##S.x, aF1_##S.y);                                \
                p.w = (int)cvtpk(aF1_##S.z, aF1_##S.w);                                \
                *(int4*)(&As[sub][buf][ar * 40 + ac]) = p;                             \
            }                                                                          \
            if (BPK) {                                                                 \
                Bd[sub][buf][(n4 + 0) * 20 + kp] = (unsigned)bP_##S.x;                 \
                Bd[sub][buf][(n4 + 1) * 20 + kp] = (unsigned)bP_##S.y;                 \
                Bd[sub][buf][(n4 + 2) * 20 + kp] = (unsigned)bP_##S.z;                 \
                Bd[sub][buf][(n4 + 3) * 20 + kp] = (unsigned)bP_##S.w;                 \
            } else {                                                                   \
                const float bl[4] = {bR0_##S.x, bR0_##S.y, bR0_##S.z, bR0_##S.w};      \
                const float bh[4] = {bR1_##S.x, bR1_##S.y, bR1_##S.z, bR1_##S.w};      \
                _Pragma("unroll")                                                      \
                for (int i = 0; i < 4; ++i)                                            \
                    Bd[sub][buf][(n4 + i) * 20 + kp] = cvtpk(bl[i], bh[i]);            \
            }                                                                          \
        } while (0)

    #define COMP(buf)                                                                  \
        do {                                                                           \
            bf16x8 bf = *(const bf16x8*)(&Bd[sub][buf][(w * 16 + r16) * 20 + quad * 4]);\
            bf16x8 a0 = *(const bf16x8*)(&As[sub][buf][(0  + r16) * 40 + quad * 8]);   \
            bf16x8 a1 = *(const bf16x8*)(&As[sub][buf][(16 + r16) * 40 + quad * 8]);   \
            bf16x8 a2 = *(const bf16x8*)(&As[sub][buf][(32 + r16) * 40 + quad * 8]);   \
            bf16x8 a3 = *(const bf16x8*)(&As[sub][buf][(48 + r16) * 40 + quad * 8]);   \
            c0 = __builtin_amdgcn_mfma_f32_16x16x32_bf16(a0, bf, c0, 0, 0, 0);         \
            c1 = __builtin_amdgcn_mfma_f32_16x16x32_bf16(a1, bf, c1, 0, 0, 0);         \
            c2 = __builtin_amdgcn_mfma_f32_16x16x32_bf16(a2, bf, c2, 0, 0, 0);         \
            c3 = __builtin_amdgcn_mfma_f32_16x16x32_bf16(a3, bf, c3, 0, 0, 0);         \
        } while (0)

    // prologue: tiles kb, kb+32 in flight; tile kb staged to buf0
    LOAD_T(0, kb);
    LOAD_T(1, kb + 32);
    STORE_T(0, 0);
    int cur = 0;
    // main loop: two tiles per trip, one barrier per tile
    for (int k0 = kb; k0 < ke; k0 += 64) {
        if (k0 + 64 < ke) LOAD_T(0, k0 + 64);
        __syncthreads();            // buf[cur] (tile k0) ready; prior reads of buf[cur^1] done
        COMP(cur);
        STORE_T(1, cur ^ 1);        // tile k0+32 (loads issued one tile ago)
        cur ^= 1;
        if (k0 + 96 < ke) LOAD_T(1, k0 + 96);
        __syncthreads();            // buf[cur] (tile k0+32) ready
        COMP(cur);
        if (k0 + 64 < ke) { STORE_T(0, cur ^ 1); cur ^= 1; }
    }
    #undef LOAD_T
    #undef STORE_T
    #undef COMP

    f32x4 frags[4] = {c0, c1, c2, c3};

    if (SPLIT) {
        if (sub == 1) {
            #pragma unroll
            for (int f = 0; f < 4; ++f)
                #pragma unroll
                for (int rg = 0; rg < 4; ++rg)
                    red[(f * 16 + quad * 4 + rg) * 64 + w * 16 + r16] = frags[f][rg];
        }
        __syncthreads();
        if (sub == 1) return;
        #pragma unroll
        for (int f = 0; f < 4; ++f)
            #pragma unroll
            for (int rg = 0; rg < 4; ++rg)
                frags[f][rg] += red[(f * 16 + quad * 4 + rg) * 64 + w * 16 + r16];
    }

    const int col = n0 + w * 16 + r16;
    const float bval = bias[col];
    float local = 0.f;
    #pragma unroll
    for (int f = 0; f < 4; ++f) {
        #pragma unroll
        for (int rg = 0; rg < 4; ++rg) {
            const int row = m0 + f * 16 + quad * 4 + rg;  // C/D: col=lane&15, row=quad*4+reg (m89)
            const float v = frags[f][rg] + bval;
            if (OUT == 0) {
                Cf[(size_t)row * Nn + col] = fmaxf(v, 0.f);
            } else if (OUT == 1) {
                Cb[(size_t)row * Nn + col] = f2bf(fmaxf(v, 0.f));
            } else {
                const float d = X[(size_t)row * Nn + col] - v;
                local += d * d;
            }
        }
    }
    if (OUT == 2) {
        #pragma unroll
        for (int off = 32; off; off >>= 1) local += __shfl_xor(local, off);
        if (l == 0) atomicAdd(acc, local);
    }
}

// ============ GEMM2 (latent = h1@We2+b2), fp32 VALU, 64x64 tile, in-block 2-way K-split ============
__global__ __launch_bounds__(512) void k_gemm2(
    const float* __restrict__ A,     // [512,2048]
    const float* __restrict__ B,     // [2048,256]
    const float* __restrict__ bias,  // [256]
    float* __restrict__ C)           // [512,256]
{
    __shared__ float AT[2][32 * 68];
    __shared__ float Bs[2][32 * 68];
    __shared__ float red[64 * 64];
    const int t = threadIdx.x;
    const int sub = t >> 8, tt = t & 255;
    const int m0 = blockIdx.y * 64, n0 = blockIdx.x * 64;
    const int ti = tt >> 4, tj = tt & 15;
    const int ar = tt >> 2, ac = (tt & 3) * 8;
    const int bk = tt >> 3, bc = (tt & 7) * 8;
    const int kbase = sub * 1024;
    float accm[4][4] = {{0.f}};

    for (int k0 = 0; k0 < 1024; k0 += 32) {
        const int kk0 = kbase + k0;
        const float4 a0 = *(const float4*)(A + (size_t)(m0 + ar) * HENC + kk0 + ac);
        const float4 a1 = *(const float4*)(A + (size_t)(m0 + ar) * HENC + kk0 + ac + 4);
        const float av[8] = {a0.x, a0.y, a0.z, a0.w, a1.x, a1.y, a1.z, a1.w};
        #pragma unroll
        for (int e = 0; e < 8; ++e) AT[sub][(ac + e) * 68 + ar] = av[e];
        *(float4*)(&Bs[sub][bk * 68 + bc])     = *(const float4*)(B + (size_t)(kk0 + bk) * EMB + n0 + bc);
        *(float4*)(&Bs[sub][bk * 68 + bc + 4]) = *(const float4*)(B + (size_t)(kk0 + bk) * EMB + n0 + bc + 4);
        __syncthreads();
        #pragma unroll 8
        for (int kk = 0; kk < 32; ++kk) {
            const float4 a = *(const float4*)(&AT[sub][kk * 68 + ti * 4]);
            const float4 b = *(const float4*)(&Bs[sub][kk * 68 + tj * 4]);
            accm[0][0] += a.x * b.x; accm[0][1] += a.x * b.y; accm[0][2] += a.x * b.z; accm[0][3] += a.x * b.w;
            accm[1][0] += a.y * b.x; accm[1][1] += a.y * b.y; accm[1][2] += a.y * b.z; accm[1][3] += a.y * b.w;
            accm[2][0] += a.z * b.x; accm[2][1] += a.z * b.y; accm[2][2] += a.z * b.z; accm[2][3] += a.z * b.w;
            accm[3][0] += a.w * b.x; accm[3][1] += a.w * b.y; accm[3][2] += a.w * b.z; accm[3][3] += a.w * b.w;
        }
        __syncthreads();
    }

    if (sub == 1) {
        #pragma unroll
        for (int i = 0; i < 4; ++i)
            #pragma unroll
            for (int j = 0; j < 4; ++j)
                red[(ti * 4 + i) * 64 + tj * 4 + j] = accm[i][j];
    }
    __syncthreads();
    if (sub == 0) {
        #pragma unroll
        for (int i = 0; i < 4; ++i) {
            const int row = m0 + ti * 4 + i;
            #pragma unroll
            for (int j = 0; j < 4; ++j) {
                const int colj = n0 + tj * 4 + j;
                const float v = (accm[i][j] + red[(ti * 4 + i) * 64 + tj * 4 + j]) + bias[colj];
                C[(size_t)row * EMB + colj] = v;
            }
        }
    }
}

// ---------------- row norms per branch ----------------
__global__ void k_sn(const float* __restrict__ latent, float* __restrict__ sn) {
    const int idx = blockIdx.x * blockDim.x + threadIdx.x;
    if (idx >= 1024) return;
    const int br = idx >> 9, r = idx & 511;
    const float* p = latent + (size_t)r * EMB + br * BR;
    float s = 0.f;
    for (int c = 0; c < BR; ++c) s += p[c] * p[c];
    sn[br * 512 + r] = s;
}

// ---------------- full distance matrix (Gram formula, as reference MST path) ----------------
__global__ __launch_bounds__(256) void k_dist(const float* __restrict__ latent,
                                              const float* __restrict__ sn,
                                              float* __restrict__ D)
{
    const int branch = blockIdx.y;
    const int ti = blockIdx.x >> 3, tj = blockIdx.x & 7;
    const int i0 = ti * 64, j0 = tj * 64;
    __shared__ float LiT[64 * 65];
    __shared__ float LjT[64 * 65];
    const int t = threadIdx.x;
    const int pi = t >> 4, pj = t & 15;
    float dot[4][4] = {{0.f}};

    for (int kc = 0; kc < BR; kc += 64) {
        for (int idx = t; idx < 1024; idx += 256) {
            const int r = idx >> 4, kq = (idx & 15) * 4;
            const float4 vi = *(const float4*)(latent + (size_t)(i0 + r) * EMB + branch * BR + kc + kq);
            const float4 vj = *(const float4*)(latent + (size_t)(j0 + r) * EMB + branch * BR + kc + kq);
            LiT[(kq + 0) * 65 + r] = vi.x; LiT[(kq + 1) * 65 + r] = vi.y;
            LiT[(kq + 2) * 65 + r] = vi.z; LiT[(kq + 3) * 65 + r] = vi.w;
            LjT[(kq + 0) * 65 + r] = vj.x; LjT[(kq + 1) * 65 + r] = vj.y;
            LjT[(kq + 2) * 65 + r] = vj.z; LjT[(kq + 3) * 65 + r] = vj.w;
        }
        __syncthreads();
        for (int k = 0; k < 64; ++k) {
            float a[4], b[4];
            #pragma unroll
            for (int i = 0; i < 4; ++i) a[i] = LiT[k * 65 + pi * 4 + i];
            #pragma unroll
            for (int j = 0; j < 4; ++j) b[j] = LjT[k * 65 + pj * 4 + j];
            #pragma unroll
            for (int i = 0; i < 4; ++i)
                #pragma unroll
                for (int j = 0; j < 4; ++j) dot[i][j] += a[i] * b[j];
        }
        __syncthreads();
    }

    const float* snb = sn + branch * 512;
    float* Db = D + (size_t)branch * 512 * 512;
    #pragma unroll
    for (int i = 0; i < 4; ++i) {
        const int gi = i0 + pi * 4 + i;
        #pragma unroll
        for (int j = 0; j < 4; ++j) {
            const int gj = j0 + pj * 4 + j;
            const float d2 = snb[gi] + snb[gj] - 2.0f * dot[i][j];
            Db[(size_t)gi * 512 + gj] = sqrtf(fmaxf(d2, 0.0f));
        }
    }
}

// ---------------- Boruvka MST: parallel rounds replace Prim's 511-long serial chain ----------------
__global__ __launch_bounds__(1024) void k_prim(const float* __restrict__ D,
                                               float2* __restrict__ mstb,
                                               float* __restrict__ acc)
{
    const int branch = blockIdx.x;
    const float* Db = D + (size_t)branch * 512 * 512;
    const int t = threadIdx.x;
    const int wid = t >> 6;      // wave id 0..15
    const int l = t & 63;
    const int l8 = l << 3;

    __shared__ unsigned short comp16[512];   // component label per vertex (a root vertex id)
    __shared__ unsigned       parent[512];   // hooking forest, per round
    __shared__ unsigned short minj[512];     // per-vertex argmin column
    __shared__ unsigned       minwb[512];    // per-vertex min weight bits (f32, positive -> u32 ordered)
    __shared__ unsigned       cminw[512];    // per-component min weight bits
    __shared__ unsigned       csrc[512];     // per-component winning vertex
    __shared__ float          elist[512];    // emitted MST edge weights
    __shared__ int            ne_sh;

    const unsigned SENT = 0x7f61b1e6u;       // bits of 3.0e38f (masked-out sentinel)

    for (int i = t; i < 512; i += 1024) comp16[i] = (unsigned short)i;
    if (t == 0) ne_sh = 0;

    // prewarm D into this XCD's L2 (1 MB, every 64B line)
    float s = 0.f;
    for (int i = t; i < 16384; i += 1024) s += Db[(size_t)i * 16];
    if (s == -1e30f) acc[3] = s;  // never true; keeps prewarm loads alive
    __syncthreads();

    int ne = 0;
    for (int round = 0; round < 12 && ne < 511; ++round) {
        for (int i = t; i < 512; i += 1024) {
            cminw[i] = 0xFFFFFFFFu;
            csrc[i]  = 0xFFFFFFFFu;
            parent[i] = (unsigned)i;
        }
        __syncthreads();

        // hoist this lane's component slice (comp16 is frozen during the scan phase)
        const u16x8 cj = *(const u16x8*)(&comp16[l8]);

        // per-vertex masked argmin over its row; one wave per vertex, vertices independent
        for (int v = wid; v < 512; v += 16) {
            const unsigned cv = comp16[v];   // uniform-address LDS broadcast
            const float4 d0 = *(const float4*)(Db + (size_t)v * 512 + l8);
            const float4 d1 = *(const float4*)(Db + (size_t)v * 512 + l8 + 4);
            const float vv[8] = {d0.x, d0.y, d0.z, d0.w, d1.x, d1.y, d1.z, d1.w};
            float best = 3.0e38f; int bi = 0;
            #pragma unroll
            for (int e = 0; e < 8; ++e) {
                const float m = ((unsigned)cj[e] == cv) ? 3.0e38f : vv[e];
                if (m < best) { best = m; bi = e; }
            }
            const float gr = wavemin_f(best);
            const unsigned gbits = (unsigned)__builtin_amdgcn_readlane(
                __builtin_bit_cast(int, gr), 63);
            const float g = __builtin_bit_cast(float, gbits);
            const unsigned long long msk = __ballot(best == g);
            const int src = __ffsll((long long)msk) - 1;
            const int jg = __builtin_amdgcn_readlane(l8 + bi, src);
            if (l == 0) {
                minwb[v] = (gbits == SENT) ? 0xFFFFFFFFu : gbits;
                minj[v]  = (unsigned short)jg;
                if (gbits != SENT) atomicMin(&cminw[cv], gbits);
            }
        }
        __syncthreads();

        // per-component winner vertex (any vertex attaining the component min)
        for (int v = t; v < 512; v += 1024) {
            const unsigned mw = minwb[v];
            if (mw != 0xFFFFFFFFu && mw == cminw[comp16[v]])
                atomicMin(&csrc[comp16[v]], (unsigned)v);
        }
        __syncthreads();

        // emit + hook per component root
        for (int c = t; c < 512; c += 1024) {
            const unsigned sv = csrc[c];
            if (sv != 0xFFFFFFFFu) {
                const unsigned wbits = cminw[c];
                const unsigned j = minj[sv];
                const unsigned c2 = comp16[j];
                const bool mutual = (cminw[c2] == wbits);  // distinct weights -> same edge
                if (!mutual || (unsigned)c < c2)
                    elist[atomicAdd(&ne_sh, 1)] = __builtin_bit_cast(float, wbits);
                parent[c] = (mutual && (unsigned)c < c2) ? (unsigned)c : c2;
            }
        }
        __syncthreads();

        // pointer jumping (chains <= 512 -> 9 doubling passes; u32 races are benign/monotone)
        for (int pj = 0; pj < 9; ++pj) {
            for (int i = t; i < 512; i += 1024) parent[i] = parent[parent[i]];
            __syncthreads();
        }
        for (int i = t; i < 512; i += 1024) comp16[i] = (unsigned short)parent[comp16[i]];
        __syncthreads();
        ne = ne_sh;
    }

    for (int i = t; i < 511; i += 1024) {
        const float w = elist[i];
        mstb[branch * 511 + i] = make_float2(w, ATOLC + RTOL * fabsf(w));
    }
}

// ---------------- loss: pdist (diff formula) + band scan + |ETA - d| ----------------
__global__ __launch_bounds__(256) void k_loss(const float* __restrict__ latent,
                                              const float2* __restrict__ mstb,
                                              float* __restrict__ acc)
{
    const int branch = blockIdx.y;
    int bid = blockIdx.x, ti = 0;
    while (bid >= 8 - ti) { bid -= 8 - ti; ti++; }
    const int tj = ti + bid;
    const int i0 = ti * 64, j0 = tj * 64;
    __shared__ float LiT[64 * 65];
    __shared__ float LjT[64 * 65];
    const int t = threadIdx.x;
    const int pi = t >> 4, pj = t & 15;
    float d2[16];
    #pragma unroll
    for (int p = 0; p < 16; ++p) d2[p] = 0.f;

    for (int kc = 0; kc < BR; kc += 64) {
        for (int idx = t; idx < 1024; idx += 256) {
            const int r = idx >> 4, kq = (idx & 15) * 4;
            const float4 vi = *(const float4*)(latent + (size_t)(i0 + r) * EMB + branch * BR + kc + kq);
            const float4 vj = *(const float4*)(latent + (size_t)(j0 + r) * EMB + branch * BR + kc + kq);
            LiT[(kq + 0) * 65 + r] = vi.x; LiT[(kq + 1) * 65 + r] = vi.y;
            LiT[(kq + 2) * 65 + r] = vi.z; LiT[(kq + 3) * 65 + r] = vi.w;
            LjT[(kq + 0) * 65 + r] = vj.x; LjT[(kq + 1) * 65 + r] = vj.y;
            LjT[(kq + 2) * 65 + r] = vj.z; LjT[(kq + 3) * 65 + r] = vj.w;
        }
        __syncthreads();
        for (int k = 0; k < 64; ++k) {
            float a[4], b[4];
            #pragma unroll
            for (int i = 0; i < 4; ++i) a[i] = LiT[k * 65 + pi * 4 + i];
            #pragma unroll
            for (int j = 0; j < 4; ++j) b[j] = LjT[k * 65 + pj * 4 + j];
            #pragma unroll
            for (int i = 0; i < 4; ++i)
                #pragma unroll
                for (int j = 0; j < 4; ++j) {
                    const float df = a[i] - b[j];
                    d2[i * 4 + j] += df * df;
                }
        }
        __syncthreads();
    }

    float dd[16]; int valid[16];
    #pragma unroll
    for (int i = 0; i < 4; ++i)
        #pragma unroll
        for (int j = 0; j < 4; ++j) {
            const int gi = i0 + pi * 4 + i, gj = j0 + pj * 4 + j;
            dd[i * 4 + j] = sqrtf(d2[i * 4 + j]);
            valid[i * 4 + j] = (gi < gj);
        }
    const float2* mbp = mstb + branch * 511;
    unsigned int mm = 0;
    for (int m = 0; m < 511; ++m) {
        const float2 mv = mbp[m];
        #pragma unroll
        for (int p = 0; p < 16; ++p)
            if (fabsf(dd[p] - mv.x) <= mv.y) mm |= (1u << p);
    }
    float sloc = 0.f;
    #pragma unroll
    for (int p = 0; p < 16; ++p)
        if (valid[p] && ((mm >> p) & 1u)) sloc += fabsf(ETA - dd[p]);
    #pragma unroll
    for (int off = 32; off; off >>= 1) sloc += __shfl_xor(sloc, off);
    if ((t & 63) == 0) atomicAdd(&acc[1], sloc);
}

__global__ void k_final(const float* __restrict__ acc, float* __restrict__ out) {
    if (threadIdx.x == 0) {
        out[0] = acc[0] / (float)((size_t)NPTS * DIN) + acc[1];
    }
}

extern "C" void kernel_launch(void* const* d_in, const int* in_sizes, int n_in,
                              void* d_out, int out_size, void* d_ws, size_t ws_size,
                              hipStream_t stream) {
    (void)in_sizes; (void)n_in; (void)out_size;
    const float* x   = (const float*)d_in[0];
    const float* We1 = (const float*)d_in[1];
    const float* be1 = (const float*)d_in[2];
    const float* We2 = (const float*)d_in[3];
    const float* be2 = (const float*)d_in[4];
    const float* Wd1 = (const float*)d_in[5];
    const float* bd1 = (const float*)d_in[6];
    const float* Wd2 = (const float*)d_in[7];
    const float* bd2 = (const float*)d_in[8];

    // ws layout:
    //   low region (as before): acc @0, sn @4096, mstb @8192, latent @16384 (512 KB)
    //   h1 @540672 (4 MB) / Dm aliases / h2b aliases
    //   fast path adds: xb @8MB (8MB), We1p @16MB (32MB), Wd2p @48MB (32MB), Wd1p @80MB (1MB)
    char* ws = (char*)d_ws;
    float*          acc    = (float*)(ws);
    float*          sn     = (float*)(ws + 4096);
    float2*         mstb   = (float2*)(ws + 8192);
    float*          latent = (float*)(ws + 16384);
    float*          h1     = (float*)(ws + 540672);
    float*          Dm     = (float*)(ws + 540672);
    unsigned short* h2b    = (unsigned short*)(ws + 540672);

    const size_t MB = 1024u * 1024u;
    unsigned*       xb   = (unsigned*)(ws + 8 * MB);
    unsigned*       We1p = (unsigned*)(ws + 16 * MB);
    unsigned*       Wd2p = (unsigned*)(ws + 48 * MB);
    unsigned*       Wd1p = (unsigned*)(ws + 80 * MB);
    const bool fast = ws_size >= 81 * MB;

    k_init<<<1, 64, 0, stream>>>(acc);

    if (fast) {
        // pre-convert operands to bf16 / k-pair-packed dwords (halves GEMM operand bytes,
        // removes all per-tile f32->bf16 conversion VALU from GEMM staging)
        k_cvt <<<2048, 256, 0, stream>>>(x, xb);
        k_pack<<<8192, 256, 0, stream>>>(We1, We1p, HENC);
        k_pack<<<8192, 256, 0, stream>>>(Wd2, Wd2p, DIN);
        k_pack<<< 256, 256, 0, stream>>>(Wd1, Wd1p, HDEC);

        k_mfma<0, 1, 1, 1><<<dim3(HENC / 64, NPTS / 64), 512, 0, stream>>>(xb, We1p, be1, h1, nullptr, nullptr, nullptr, HENC, DIN);
        k_gemm2<<<dim3(EMB / 64, NPTS / 64), 512, 0, stream>>>(h1, We2, be2, latent);
        k_sn<<<4, 256, 0, stream>>>(latent, sn);
        k_dist<<<dim3(64, 2), 256, 0, stream>>>(latent, sn, Dm);
        k_prim<<<2, 1024, 0, stream>>>(Dm, mstb, acc);
        k_loss<<<dim3(36, 2), 256, 0, stream>>>(latent, mstb, acc);
        k_mfma<1, 0, 1, 1><<<dim3(HDEC / 64, NPTS / 64), 512, 0, stream>>>(latent, Wd1p, bd1, nullptr, h2b, nullptr, nullptr, HDEC, EMB);
        k_mfma<2, 1, 0, 1><<<dim3(DIN / 64, NPTS / 64), 256, 0, stream>>>(h2b, Wd2p, bd2, nullptr, nullptr, x, acc, DIN, HDEC);
    } else {
        // fallback: round-4 structure (f32 operands, cvt_pk in staging)
        k_mfma<0, 0, 1, 0><<<dim3(HENC / 64, NPTS / 64), 512, 0, stream>>>(x, We1, be1, h1, nullptr, nullptr, nullptr, HENC, DIN);
        k_gemm2<<<dim3(EMB / 64, NPTS / 64), 512, 0, stream>>>(h1, We2, be2, latent);
        k_sn<<<4, 256, 0, stream>>>(latent, sn);
        k_dist<<<dim3(64, 2), 256, 0, stream>>>(latent, sn, Dm);
        k_prim<<<2, 1024, 0, stream>>>(Dm, mstb, acc);
        k_loss<<<dim3(36, 2), 256, 0, stream>>>(latent, mstb, acc);
        k_mfma<1, 0, 1, 0><<<dim3(HDEC / 64, NPTS / 64), 512, 0, stream>>>(latent, Wd1, bd1, nullptr, h2b, nullptr, nullptr, HDEC, EMB);
        k_mfma<2, 1, 0, 0><<<dim3(DIN / 64, NPTS / 64), 256, 0, stream>>>(h2b, Wd2, bd2, nullptr, nullptr, x, acc, DIN, HDEC);
    }
    k_final<<<1, 64, 0, stream>>>(acc, (float*)d_out);
}

// Round 6
// 589.761 us; speedup vs baseline: 1.5154x; 1.0659x over previous
//
#include <hip/hip_runtime.h>
#include <stdint.h>

#define NPTS 512
#define DIN  8192
#define HENC 2048
#define EMB  256
#define HDEC 2048
#define BR   128
#define ETA  2.0f
#define RTOL 1e-4f
#define ATOLC 1e-8f

typedef __attribute__((ext_vector_type(8))) short bf16x8;
typedef __attribute__((ext_vector_type(4))) float f32x4;
typedef __attribute__((ext_vector_type(8))) unsigned short u16x8;

__device__ __forceinline__ unsigned short f2bf(float f) {
    unsigned int x = __builtin_bit_cast(unsigned int, f);
    unsigned int lsb = (x >> 16) & 1u;
    x += 0x7fffu + lsb;
    return (unsigned short)(x >> 16);
}

// packed f32x2 -> bf16x2 (RNE, matches f2bf bitwise): D[15:0]=bf16(lo), D[31:16]=bf16(hi)
__device__ __forceinline__ unsigned cvtpk(float lo, float hi) {
    unsigned d;
    asm("v_cvt_pk_bf16_f32 %0, %1, %2" : "=v"(d) : "v"(lo), "v"(hi));
    return d;
}

// DPP-based wave64 min-reduce (VALU-latency cross-lane; result valid in lane 63).
template<int CTRL>
__device__ __forceinline__ float dppmin_f(float x) {
    int xi = __builtin_bit_cast(int, x);
    int f = __builtin_amdgcn_update_dpp(xi, xi, CTRL, 0xf, 0xf, false);
    return fminf(x, __builtin_bit_cast(float, f));
}
__device__ __forceinline__ float wavemin_f(float x) {
    x = dppmin_f<0x111>(x);  // row_shr:1
    x = dppmin_f<0x112>(x);  // row_shr:2
    x = dppmin_f<0x114>(x);  // row_shr:4
    x = dppmin_f<0x118>(x);  // row_shr:8
    x = dppmin_f<0x142>(x);  // row_bcast:15
    x = dppmin_f<0x143>(x);  // row_bcast:31
    return x;
}

__global__ void k_init(float* acc) {
    if (threadIdx.x < 4) acc[threadIdx.x] = 0.0f;
}

// ---------------- pre-convert passes (run once; halve GEMM operand bytes) ----------------
// x f32 -> bf16 row-major (same layout)
__global__ __launch_bounds__(256) void k_cvt(const float* __restrict__ in,
                                             unsigned* __restrict__ out)
{
    const size_t id = (size_t)blockIdx.x * 256 + threadIdx.x;   // one int4 = 8 floats
    const float4 a = *(const float4*)(in + id * 8);
    const float4 b = *(const float4*)(in + id * 8 + 4);
    int4 o;
    o.x = (int)cvtpk(a.x, a.y); o.y = (int)cvtpk(a.z, a.w);
    o.z = (int)cvtpk(b.x, b.y); o.w = (int)cvtpk(b.z, b.w);
    *(int4*)(out + id * 4) = o;
}

// B [K][N] f32 -> [K/2][N] u32, dword = bf16(B[2kd][n]) | bf16(B[2kd+1][n])<<16
// (exactly the Bd LDS dword format -> GEMM B staging becomes pure copy)
__global__ __launch_bounds__(256) void k_pack(const float* __restrict__ in,
                                              unsigned* __restrict__ out, int N)
{
    const int id = blockIdx.x * 256 + threadIdx.x;   // one int4 = 4 output dwords
    const int perRow = N >> 2;
    const int row = id / perRow;          // kd
    const int col = (id - row * perRow) << 2;
    const float4 r0 = *(const float4*)(in + (size_t)(2 * row) * N + col);
    const float4 r1 = *(const float4*)(in + (size_t)(2 * row + 1) * N + col);
    int4 o;
    o.x = (int)cvtpk(r0.x, r1.x); o.y = (int)cvtpk(r0.y, r1.y);
    o.z = (int)cvtpk(r0.z, r1.z); o.w = (int)cvtpk(r0.w, r1.w);
    *(int4*)(out + (size_t)row * N + col) = o;
}

// ============ bf16 MFMA GEMM: 64x64 tile, BK=32, LDS dbuf, prefetch-2, optional K-split ============
// OUT==0: Cf = relu(A@B+bias) f32   (GEMM1: h1)
// OUT==1: Cb = bf16(relu(A@B+bias)) (GEMM3: h2b)
// OUT==2: acc += sum((X-(A@B+bias))^2) (GEMM4, recon never stored)
// A_BF16==1: A is bf16 ushort; else f32 converted in staging (cvt_pk).
// BPK==1: B is pre-packed u32 [K/2][N] (k-pair dwords) -> staging is pure copy.
// SPLIT==1: 512 threads, two 256-thread halves each do K/2 with own LDS dbuf, LDS-reduce at end.
template<int OUT, int A_BF16, int SPLIT, int BPK>
__global__ __launch_bounds__(SPLIT ? 512 : 256) void k_mfma(
    const void* __restrict__ Araw,
    const void* __restrict__ Braw,
    const float* __restrict__ bias,
    float* __restrict__ Cf,
    unsigned short* __restrict__ Cb,
    const float* __restrict__ X,
    float* __restrict__ acc,
    int Nn, int K)
{
    __shared__ unsigned short As[SPLIT ? 2 : 1][2][64 * 40];  // [sub][buf][m*40+k]
    __shared__ unsigned int   Bd[SPLIT ? 2 : 1][2][64 * 20];  // [sub][buf][n*20+kd]
    __shared__ float          red[SPLIT ? 4096 : 1];
    const int t = threadIdx.x;
    const int sub = SPLIT ? (t >> 8) : 0;
    const int tt = SPLIT ? (t & 255) : t;
    const int w = tt >> 6;
    const int l = tt & 63;
    const int quad = l >> 4;
    const int r16 = l & 15;
    const int n0 = blockIdx.x * 64;
    const int m0 = blockIdx.y * 64;

    const int ar = tt >> 2, ac = (tt & 3) * 8;     // A staging
    const int kp = tt & 15, n4 = (tt >> 4) * 4;    // B staging

    const int kb = sub * (K >> SPLIT);
    const int ke = kb + (K >> SPLIT);

    f32x4 c0 = {0,0,0,0}, c1 = {0,0,0,0}, c2 = {0,0,0,0}, c3 = {0,0,0,0};

    int4   aI_0, aI_1, bP_0, bP_1;
    float4 aF0_0, aF1_0, bR0_0, bR1_0;
    float4 aF0_1, aF1_1, bR0_1, bR1_1;

    #define LOAD_T(S, k0)                                                              \
        do {                                                                           \
            if (A_BF16) {                                                              \
                const unsigned short* A = (const unsigned short*)Araw;                 \
                aI_##S = *(const int4*)(A + (size_t)(m0 + ar) * K + (k0) + ac);        \
            } else {                                                                   \
                const float* A = (const float*)Araw;                                   \
                aF0_##S = *(const float4*)(A + (size_t)(m0 + ar) * K + (k0) + ac);     \
                aF1_##S = *(const float4*)(A + (size_t)(m0 + ar) * K + (k0) + ac + 4); \
            }                                                                          \
            if (BPK) {                                                                 \
                const unsigned* Bp = (const unsigned*)Braw;                            \
                bP_##S = *(const int4*)(Bp + (size_t)(((k0) >> 1) + kp) * Nn + n0 + n4);\
            } else {                                                                   \
                const float* B = (const float*)Braw;                                   \
                bR0_##S = *(const float4*)(B + (size_t)((k0) + 2 * kp) * Nn + n0 + n4);\
                bR1_##S = *(const float4*)(B + (size_t)((k0) + 2 * kp + 1) * Nn + n0 + n4);\
            }                                                                          \
        } while (0)

    #define STORE_T(S, buf)                                                            \
        do {                                                                           \
            if (A_BF16) {                                                              \
                *(int4*)(&As[sub][buf][ar * 40 + ac]) = aI_##S;                        \
            } else {                                                                   \
                int4 p;                                                                \
                p.x = (int)cvtpk(aF0_##S.x, aF0_##S.y);                                \
                p.y = (int)cvtpk(aF0_##S.z, aF0_##S.w);                                \
                p.z = (int)cvtpk(aF1_##S.x, aF1_##S.y);                                \
                p.w = (int)cvtpk(aF1_##S.z, aF1_##S.w);                                \
                *(int4*)(&As[sub][buf][ar * 40 + ac]) = p;                             \
            }                                                                          \
            if (BPK) {                                                                 \
                Bd[sub][buf][(n4 + 0) * 20 + kp] = (unsigned)bP_##S.x;                 \
                Bd[sub][buf][(n4 + 1) * 20 + kp] = (unsigned)bP_##S.y;                 \
                Bd[sub][buf][(n4 + 2) * 20 + kp] = (unsigned)bP_##S.z;                 \
                Bd[sub][buf][(n4 + 3) * 20 + kp] = (unsigned)bP_##S.w;                 \
            } else {                                                                   \
                const float bl[4] = {bR0_##S.x, bR0_##S.y, bR0_##S.z, bR0_##S.w};      \
                const float bh[4] = {bR1_##S.x, bR1_##S.y, bR1_##S.z, bR1_##S.w};      \
                _Pragma("unroll")                                                      \
                for (int i = 0; i < 4; ++i)                                            \
                    Bd[sub][buf][(n4 + i) * 20 + kp] = cvtpk(bl[i], bh[i]);            \
            }                                                                          \
        } while (0)

    #define COMP(buf)                                                                  \
        do {                                                                           \
            bf16x8 bf = *(const bf16x8*)(&Bd[sub][buf][(w * 16 + r16) * 20 + quad * 4]);\
            bf16x8 a0 = *(const bf16x8*)(&As[sub][buf][(0  + r16) * 40 + quad * 8]);   \
            bf16x8 a1 = *(const bf16x8*)(&As[sub][buf][(16 + r16) * 40 + quad * 8]);   \
            bf16x8 a2 = *(const bf16x8*)(&As[sub][buf][(32 + r16) * 40 + quad * 8]);   \
            bf16x8 a3 = *(const bf16x8*)(&As[sub][buf][(48 + r16) * 40 + quad * 8]);   \
            c0 = __builtin_amdgcn_mfma_f32_16x16x32_bf16(a0, bf, c0, 0, 0, 0);         \
            c1 = __builtin_amdgcn_mfma_f32_16x16x32_bf16(a1, bf, c1, 0, 0, 0);         \
            c2 = __builtin_amdgcn_mfma_f32_16x16x32_bf16(a2, bf, c2, 0, 0, 0);         \
            c3 = __builtin_amdgcn_mfma_f32_16x16x32_bf16(a3, bf, c3, 0, 0, 0);         \
        } while (0)

    // prologue: tiles kb, kb+32 in flight; tile kb staged to buf0
    LOAD_T(0, kb);
    LOAD_T(1, kb + 32);
    STORE_T(0, 0);
    int cur = 0;
    // main loop: two tiles per trip, one barrier per tile
    for (int k0 = kb; k0 < ke; k0 += 64) {
        if (k0 + 64 < ke) LOAD_T(0, k0 + 64);
        __syncthreads();            // buf[cur] (tile k0) ready; prior reads of buf[cur^1] done
        COMP(cur);
        STORE_T(1, cur ^ 1);        // tile k0+32 (loads issued one tile ago)
        cur ^= 1;
        if (k0 + 96 < ke) LOAD_T(1, k0 + 96);
        __syncthreads();            // buf[cur] (tile k0+32) ready
        COMP(cur);
        if (k0 + 64 < ke) { STORE_T(0, cur ^ 1); cur ^= 1; }
    }
    #undef LOAD_T
    #undef STORE_T
    #undef COMP

    f32x4 frags[4] = {c0, c1, c2, c3};

    if (SPLIT) {
        if (sub == 1) {
            #pragma unroll
            for (int f = 0; f < 4; ++f)
                #pragma unroll
                for (int rg = 0; rg < 4; ++rg)
                    red[(f * 16 + quad * 4 + rg) * 64 + w * 16 + r16] = frags[f][rg];
        }
        __syncthreads();
        if (sub == 1) return;
        #pragma unroll
        for (int f = 0; f < 4; ++f)
            #pragma unroll
            for (int rg = 0; rg < 4; ++rg)
                frags[f][rg] += red[(f * 16 + quad * 4 + rg) * 64 + w * 16 + r16];
    }

    const int col = n0 + w * 16 + r16;
    const float bval = bias[col];
    float local = 0.f;
    #pragma unroll
    for (int f = 0; f < 4; ++f) {
        #pragma unroll
        for (int rg = 0; rg < 4; ++rg) {
            const int row = m0 + f * 16 + quad * 4 + rg;  // C/D: col=lane&15, row=quad*4+reg (m89)
            const float v = frags[f][rg] + bval;
            if (OUT == 0) {
                Cf[(size_t)row * Nn + col] = fmaxf(v, 0.f);
            } else if (OUT == 1) {
                Cb[(size_t)row * Nn + col] = f2bf(fmaxf(v, 0.f));
            } else {
                const float d = X[(size_t)row * Nn + col] - v;
                local += d * d;
            }
        }
    }
    if (OUT == 2) {
        #pragma unroll
        for (int off = 32; off; off >>= 1) local += __shfl_xor(local, off);
        if (l == 0) atomicAdd(acc, local);
    }
}

// ============ GEMM2 (latent = h1@We2+b2), fp32 VALU, 64x64 tile, in-block 2-way K-split ============
__global__ __launch_bounds__(512) void k_gemm2(
    const float* __restrict__ A,     // [512,2048]
    const float* __restrict__ B,     // [2048,256]
    const float* __restrict__ bias,  // [256]
    float* __restrict__ C)           // [512,256]
{
    __shared__ float AT[2][32 * 68];
    __shared__ float Bs[2][32 * 68];
    __shared__ float red[64 * 64];
    const int t = threadIdx.x;
    const int sub = t >> 8, tt = t & 255;
    const int m0 = blockIdx.y * 64, n0 = blockIdx.x * 64;
    const int ti = tt >> 4, tj = tt & 15;
    const int ar = tt >> 2, ac = (tt & 3) * 8;
    const int bk = tt >> 3, bc = (tt & 7) * 8;
    const int kbase = sub * 1024;
    float accm[4][4] = {{0.f}};

    for (int k0 = 0; k0 < 1024; k0 += 32) {
        const int kk0 = kbase + k0;
        const float4 a0 = *(const float4*)(A + (size_t)(m0 + ar) * HENC + kk0 + ac);
        const float4 a1 = *(const float4*)(A + (size_t)(m0 + ar) * HENC + kk0 + ac + 4);
        const float av[8] = {a0.x, a0.y, a0.z, a0.w, a1.x, a1.y, a1.z, a1.w};
        #pragma unroll
        for (int e = 0; e < 8; ++e) AT[sub][(ac + e) * 68 + ar] = av[e];
        *(float4*)(&Bs[sub][bk * 68 + bc])     = *(const float4*)(B + (size_t)(kk0 + bk) * EMB + n0 + bc);
        *(float4*)(&Bs[sub][bk * 68 + bc + 4]) = *(const float4*)(B + (size_t)(kk0 + bk) * EMB + n0 + bc + 4);
        __syncthreads();
        #pragma unroll 8
        for (int kk = 0; kk < 32; ++kk) {
            const float4 a = *(const float4*)(&AT[sub][kk * 68 + ti * 4]);
            const float4 b = *(const float4*)(&Bs[sub][kk * 68 + tj * 4]);
            accm[0][0] += a.x * b.x; accm[0][1] += a.x * b.y; accm[0][2] += a.x * b.z; accm[0][3] += a.x * b.w;
            accm[1][0] += a.y * b.x; accm[1][1] += a.y * b.y; accm[1][2] += a.y * b.z; accm[1][3] += a.y * b.w;
            accm[2][0] += a.z * b.x; accm[2][1] += a.z * b.y; accm[2][2] += a.z * b.z; accm[2][3] += a.z * b.w;
            accm[3][0] += a.w * b.x; accm[3][1] += a.w * b.y; accm[3][2] += a.w * b.z; accm[3][3] += a.w * b.w;
        }
        __syncthreads();
    }

    if (sub == 1) {
        #pragma unroll
        for (int i = 0; i < 4; ++i)
            #pragma unroll
            for (int j = 0; j < 4; ++j)
                red[(ti * 4 + i) * 64 + tj * 4 + j] = accm[i][j];
    }
    __syncthreads();
    if (sub == 0) {
        #pragma unroll
        for (int i = 0; i < 4; ++i) {
            const int row = m0 + ti * 4 + i;
            #pragma unroll
            for (int j = 0; j < 4; ++j) {
                const int colj = n0 + tj * 4 + j;
                const float v = (accm[i][j] + red[(ti * 4 + i) * 64 + tj * 4 + j]) + bias[colj];
                C[(size_t)row * EMB + colj] = v;
            }
        }
    }
}

// ---------------- row norms per branch ----------------
__global__ void k_sn(const float* __restrict__ latent, float* __restrict__ sn) {
    const int idx = blockIdx.x * blockDim.x + threadIdx.x;
    if (idx >= 1024) return;
    const int br = idx >> 9, r = idx & 511;
    const float* p = latent + (size_t)r * EMB + br * BR;
    float s = 0.f;
    for (int c = 0; c < BR; ++c) s += p[c] * p[c];
    sn[br * 512 + r] = s;
}

// ---------------- full distance matrix (Gram formula, as reference MST path) ----------------
__global__ __launch_bounds__(256) void k_dist(const float* __restrict__ latent,
                                              const float* __restrict__ sn,
                                              float* __restrict__ D)
{
    const int branch = blockIdx.y;
    const int ti = blockIdx.x >> 3, tj = blockIdx.x & 7;
    const int i0 = ti * 64, j0 = tj * 64;
    __shared__ float LiT[64 * 65];
    __shared__ float LjT[64 * 65];
    const int t = threadIdx.x;
    const int pi = t >> 4, pj = t & 15;
    float dot[4][4] = {{0.f}};

    for (int kc = 0; kc < BR; kc += 64) {
        for (int idx = t; idx < 1024; idx += 256) {
            const int r = idx >> 4, kq = (idx & 15) * 4;
            const float4 vi = *(const float4*)(latent + (size_t)(i0 + r) * EMB + branch * BR + kc + kq);
            const float4 vj = *(const float4*)(latent + (size_t)(j0 + r) * EMB + branch * BR + kc + kq);
            LiT[(kq + 0) * 65 + r] = vi.x; LiT[(kq + 1) * 65 + r] = vi.y;
            LiT[(kq + 2) * 65 + r] = vi.z; LiT[(kq + 3) * 65 + r] = vi.w;
            LjT[(kq + 0) * 65 + r] = vj.x; LjT[(kq + 1) * 65 + r] = vj.y;
            LjT[(kq + 2) * 65 + r] = vj.z; LjT[(kq + 3) * 65 + r] = vj.w;
        }
        __syncthreads();
        for (int k = 0; k < 64; ++k) {
            float a[4], b[4];
            #pragma unroll
            for (int i = 0; i < 4; ++i) a[i] = LiT[k * 65 + pi * 4 + i];
            #pragma unroll
            for (int j = 0; j < 4; ++j) b[j] = LjT[k * 65 + pj * 4 + j];
            #pragma unroll
            for (int i = 0; i < 4; ++i)
                #pragma unroll
                for (int j = 0; j < 4; ++j) dot[i][j] += a[i] * b[j];
        }
        __syncthreads();
    }

    const float* snb = sn + branch * 512;
    float* Db = D + (size_t)branch * 512 * 512;
    #pragma unroll
    for (int i = 0; i < 4; ++i) {
        const int gi = i0 + pi * 4 + i;
        #pragma unroll
        for (int j = 0; j < 4; ++j) {
            const int gj = j0 + pj * 4 + j;
            const float d2 = snb[gi] + snb[gj] - 2.0f * dot[i][j];
            Db[(size_t)gi * 512 + gj] = sqrtf(fmaxf(d2, 0.0f));
        }
    }
}

// ---------------- Boruvka MST: parallel rounds replace Prim's 511-long serial chain ----------------
__global__ __launch_bounds__(1024) void k_prim(const float* __restrict__ D,
                                               float2* __restrict__ mstb,
                                               float* __restrict__ acc)
{
    const int branch = blockIdx.x;
    const float* Db = D + (size_t)branch * 512 * 512;
    const int t = threadIdx.x;
    const int wid = t >> 6;      // wave id 0..15
    const int l = t & 63;
    const int l8 = l << 3;

    __shared__ unsigned short comp16[512];   // component label per vertex (a root vertex id)
    __shared__ unsigned       parent[512];   // hooking forest, per round
    __shared__ unsigned short minj[512];     // per-vertex argmin column
    __shared__ unsigned       minwb[512];    // per-vertex min weight bits (f32, positive -> u32 ordered)
    __shared__ unsigned       cminw[512];    // per-component min weight bits
    __shared__ unsigned       csrc[512];     // per-component winning vertex
    __shared__ float          elist[512];    // emitted MST edge weights
    __shared__ int            ne_sh;

    const unsigned SENT = 0x7f61b1e6u;       // bits of 3.0e38f (masked-out sentinel)

    for (int i = t; i < 512; i += 1024) comp16[i] = (unsigned short)i;
    if (t == 0) ne_sh = 0;

    // prewarm D into this XCD's L2 (1 MB, every 64B line)
    float s = 0.f;
    for (int i = t; i < 16384; i += 1024) s += Db[(size_t)i * 16];
    if (s == -1e30f) acc[3] = s;  // never true; keeps prewarm loads alive
    __syncthreads();

    int ne = 0;
    for (int round = 0; round < 12 && ne < 511; ++round) {
        for (int i = t; i < 512; i += 1024) {
            cminw[i] = 0xFFFFFFFFu;
            csrc[i]  = 0xFFFFFFFFu;
            parent[i] = (unsigned)i;
        }
        __syncthreads();

        // hoist this lane's component slice (comp16 is frozen during the scan phase)
        const u16x8 cj = *(const u16x8*)(&comp16[l8]);

        // per-vertex masked argmin over its row; one wave per vertex, vertices independent
        for (int v = wid; v < 512; v += 16) {
            const unsigned cv = comp16[v];   // uniform-address LDS broadcast
            const float4 d0 = *(const float4*)(Db + (size_t)v * 512 + l8);
            const float4 d1 = *(const float4*)(Db + (size_t)v * 512 + l8 + 4);
            const float vv[8] = {d0.x, d0.y, d0.z, d0.w, d1.x, d1.y, d1.z, d1.w};
            float best = 3.0e38f; int bi = 0;
            #pragma unroll
            for (int e = 0; e < 8; ++e) {
                const float m = ((unsigned)cj[e] == cv) ? 3.0e38f : vv[e];
                if (m < best) { best = m; bi = e; }
            }
            const float gr = wavemin_f(best);
            const unsigned gbits = (unsigned)__builtin_amdgcn_readlane(
                __builtin_bit_cast(int, gr), 63);
            const float g = __builtin_bit_cast(float, gbits);
            const unsigned long long msk = __ballot(best == g);
            const int src = __ffsll((long long)msk) - 1;
            const int jg = __builtin_amdgcn_readlane(l8 + bi, src);
            if (l == 0) {
                minwb[v] = (gbits == SENT) ? 0xFFFFFFFFu : gbits;
                minj[v]  = (unsigned short)jg;
                if (gbits != SENT) atomicMin(&cminw[cv], gbits);
            }
        }
        __syncthreads();

        // per-component winner vertex (any vertex attaining the component min)
        for (int v = t; v < 512; v += 1024) {
            const unsigned mw = minwb[v];
            if (mw != 0xFFFFFFFFu && mw == cminw[comp16[v]])
                atomicMin(&csrc[comp16[v]], (unsigned)v);
        }
        __syncthreads();

        // emit + hook per component root
        for (int c = t; c < 512; c += 1024) {
            const unsigned sv = csrc[c];
            if (sv != 0xFFFFFFFFu) {
                const unsigned wbits = cminw[c];
                const unsigned j = minj[sv];
                const unsigned c2 = comp16[j];
                const bool mutual = (cminw[c2] == wbits);  // distinct weights -> same edge
                if (!mutual || (unsigned)c < c2)
                    elist[atomicAdd(&ne_sh, 1)] = __builtin_bit_cast(float, wbits);
                parent[c] = (mutual && (unsigned)c < c2) ? (unsigned)c : c2;
            }
        }
        __syncthreads();

        // pointer jumping (chains <= 512 -> 9 doubling passes; u32 races are benign/monotone)
        for (int pj = 0; pj < 9; ++pj) {
            for (int i = t; i < 512; i += 1024) parent[i] = parent[parent[i]];
            __syncthreads();
        }
        for (int i = t; i < 512; i += 1024) comp16[i] = (unsigned short)parent[comp16[i]];
        __syncthreads();
        ne = ne_sh;
    }

    for (int i = t; i < 511; i += 1024) {
        const float w = elist[i];
        mstb[branch * 511 + i] = make_float2(w, ATOLC + RTOL * fabsf(w));
    }
}

// ---------------- loss: pdist (diff formula) + LDS-staged band scan + |ETA - d| ----------------
__global__ __launch_bounds__(256) void k_loss(const float* __restrict__ latent,
                                              const float2* __restrict__ mstb,
                                              float* __restrict__ acc)
{
    const int branch = blockIdx.y;
    int bid = blockIdx.x, ti = 0;
    while (bid >= 8 - ti) { bid -= 8 - ti; ti++; }
    const int tj = ti + bid;
    const int i0 = ti * 64, j0 = tj * 64;
    __shared__ float LiT[64 * 65];
    __shared__ float LjT[64 * 65];
    __shared__ float2 msh[511];          // band list staged once (was: 511 global re-reads/thread)
    const int t = threadIdx.x;
    const int pi = t >> 4, pj = t & 15;
    float d2[16];
    #pragma unroll
    for (int p = 0; p < 16; ++p) d2[p] = 0.f;

    // stage mstb -> LDS; visibility covered by the first __syncthreads in the kc loop
    {
        const float2* mbp = mstb + branch * 511;
        for (int i = t; i < 511; i += 256) msh[i] = mbp[i];
    }

    for (int kc = 0; kc < BR; kc += 64) {
        for (int idx = t; idx < 1024; idx += 256) {
            const int r = idx >> 4, kq = (idx & 15) * 4;
            const float4 vi = *(const float4*)(latent + (size_t)(i0 + r) * EMB + branch * BR + kc + kq);
            const float4 vj = *(const float4*)(latent + (size_t)(j0 + r) * EMB + branch * BR + kc + kq);
            LiT[(kq + 0) * 65 + r] = vi.x; LiT[(kq + 1) * 65 + r] = vi.y;
            LiT[(kq + 2) * 65 + r] = vi.z; LiT[(kq + 3) * 65 + r] = vi.w;
            LjT[(kq + 0) * 65 + r] = vj.x; LjT[(kq + 1) * 65 + r] = vj.y;
            LjT[(kq + 2) * 65 + r] = vj.z; LjT[(kq + 3) * 65 + r] = vj.w;
        }
        __syncthreads();
        for (int k = 0; k < 64; ++k) {
            float a[4], b[4];
            #pragma unroll
            for (int i = 0; i < 4; ++i) a[i] = LiT[k * 65 + pi * 4 + i];
            #pragma unroll
            for (int j = 0; j < 4; ++j) b[j] = LjT[k * 65 + pj * 4 + j];
            #pragma unroll
            for (int i = 0; i < 4; ++i)
                #pragma unroll
                for (int j = 0; j < 4; ++j) {
                    const float df = a[i] - b[j];
                    d2[i * 4 + j] += df * df;
                }
        }
        __syncthreads();
    }

    float dd[16]; int valid[16];
    #pragma unroll
    for (int i = 0; i < 4; ++i)
        #pragma unroll
        for (int j = 0; j < 4; ++j) {
            const int gi = i0 + pi * 4 + i, gj = j0 + pj * 4 + j;
            dd[i * 4 + j] = sqrtf(d2[i * 4 + j]);
            valid[i * 4 + j] = (gi < gj);
        }
    unsigned int mm = 0;
    #pragma unroll 4
    for (int m = 0; m < 511; ++m) {
        const float2 mv = msh[m];     // LDS broadcast read; pipelines across unrolled iters
        #pragma unroll
        for (int p = 0; p < 16; ++p)
            if (fabsf(dd[p] - mv.x) <= mv.y) mm |= (1u << p);
    }
    float sloc = 0.f;
    #pragma unroll
    for (int p = 0; p < 16; ++p)
        if (valid[p] && ((mm >> p) & 1u)) sloc += fabsf(ETA - dd[p]);
    #pragma unroll
    for (int off = 32; off; off >>= 1) sloc += __shfl_xor(sloc, off);
    if ((t & 63) == 0) atomicAdd(&acc[1], sloc);
}

__global__ void k_final(const float* __restrict__ acc, float* __restrict__ out) {
    if (threadIdx.x == 0) {
        out[0] = acc[0] / (float)((size_t)NPTS * DIN) + acc[1];
    }
}

extern "C" void kernel_launch(void* const* d_in, const int* in_sizes, int n_in,
                              void* d_out, int out_size, void* d_ws, size_t ws_size,
                              hipStream_t stream) {
    (void)in_sizes; (void)n_in; (void)out_size;
    const float* x   = (const float*)d_in[0];
    const float* We1 = (const float*)d_in[1];
    const float* be1 = (const float*)d_in[2];
    const float* We2 = (const float*)d_in[3];
    const float* be2 = (const float*)d_in[4];
    const float* Wd1 = (const float*)d_in[5];
    const float* bd1 = (const float*)d_in[6];
    const float* Wd2 = (const float*)d_in[7];
    const float* bd2 = (const float*)d_in[8];

    // ws layout:
    //   low region (as before): acc @0, sn @4096, mstb @8192, latent @16384 (512 KB)
    //   h1 @540672 (4 MB) / Dm aliases / h2b aliases
    //   fast path adds: xb @8MB (8MB), We1p @16MB (32MB), Wd2p @48MB (32MB), Wd1p @80MB (1MB)
    char* ws = (char*)d_ws;
    float*          acc    = (float*)(ws);
    float*          sn     = (float*)(ws + 4096);
    float2*         mstb   = (float2*)(ws + 8192);
    float*          latent = (float*)(ws + 16384);
    float*          h1     = (float*)(ws + 540672);
    float*          Dm     = (float*)(ws + 540672);
    unsigned short* h2b    = (unsigned short*)(ws + 540672);

    const size_t MB = 1024u * 1024u;
    unsigned*       xb   = (unsigned*)(ws + 8 * MB);
    unsigned*       We1p = (unsigned*)(ws + 16 * MB);
    unsigned*       Wd2p = (unsigned*)(ws + 48 * MB);
    unsigned*       Wd1p = (unsigned*)(ws + 80 * MB);
    const bool fast = ws_size >= 81 * MB;

    k_init<<<1, 64, 0, stream>>>(acc);

    if (fast) {
        // pre-convert operands to bf16 / k-pair-packed dwords (halves GEMM operand bytes,
        // removes all per-tile f32->bf16 conversion VALU from GEMM staging)
        k_cvt <<<2048, 256, 0, stream>>>(x, xb);
        k_pack<<<8192, 256, 0, stream>>>(We1, We1p, HENC);
        k_pack<<<8192, 256, 0, stream>>>(Wd2, Wd2p, DIN);
        k_pack<<< 256, 256, 0, stream>>>(Wd1, Wd1p, HDEC);

        k_mfma<0, 1, 1, 1><<<dim3(HENC / 64, NPTS / 64), 512, 0, stream>>>(xb, We1p, be1, h1, nullptr, nullptr, nullptr, HENC, DIN);
        k_gemm2<<<dim3(EMB / 64, NPTS / 64), 512, 0, stream>>>(h1, We2, be2, latent);
        k_sn<<<4, 256, 0, stream>>>(latent, sn);
        k_dist<<<dim3(64, 2), 256, 0, stream>>>(latent, sn, Dm);
        k_prim<<<2, 1024, 0, stream>>>(Dm, mstb, acc);
        k_loss<<<dim3(36, 2), 256, 0, stream>>>(latent, mstb, acc);
        k_mfma<1, 0, 1, 1><<<dim3(HDEC / 64, NPTS / 64), 512, 0, stream>>>(latent, Wd1p, bd1, nullptr, h2b, nullptr, nullptr, HDEC, EMB);
        k_mfma<2, 1, 0, 1><<<dim3(DIN / 64, NPTS / 64), 256, 0, stream>>>(h2b, Wd2p, bd2, nullptr, nullptr, x, acc, DIN, HDEC);
    } else {
        // fallback: round-4 structure (f32 operands, cvt_pk in staging)
        k_mfma<0, 0, 1, 0><<<dim3(HENC / 64, NPTS / 64), 512, 0, stream>>>(x, We1, be1, h1, nullptr, nullptr, nullptr, HENC, DIN);
        k_gemm2<<<dim3(EMB / 64, NPTS / 64), 512, 0, stream>>>(h1, We2, be2, latent);
        k_sn<<<4, 256, 0, stream>>>(latent, sn);
        k_dist<<<dim3(64, 2), 256, 0, stream>>>(latent, sn, Dm);
        k_prim<<<2, 1024, 0, stream>>>(Dm, mstb, acc);
        k_loss<<<dim3(36, 2), 256, 0, stream>>>(latent, mstb, acc);
        k_mfma<1, 0, 1, 0><<<dim3(HDEC / 64, NPTS / 64), 512, 0, stream>>>(latent, Wd1, bd1, nullptr, h2b, nullptr, nullptr, HDEC, EMB);
        k_mfma<2, 1, 0, 0><<<dim3(DIN / 64, NPTS / 64), 256, 0, stream>>>(h2b, Wd2, bd2, nullptr, nullptr, x, acc, DIN, HDEC);
    }
    k_final<<<1, 64, 0, stream>>>(acc, (float*)d_out);
}

// Round 7
// 557.739 us; speedup vs baseline: 1.6024x; 1.0574x over previous
//
#include <hip/hip_runtime.h>
#include <stdint.h>

#define NPTS 512
#define DIN  8192
#define HENC 2048
#define EMB  256
#define HDEC 2048
#define BR   128
#define ETA  2.0f
#define RTOL 1e-4f
#define ATOLC 1e-8f

typedef __attribute__((ext_vector_type(8))) short bf16x8;
typedef __attribute__((ext_vector_type(4))) float f32x4;
typedef __attribute__((ext_vector_type(8))) unsigned short u16x8;

__device__ __forceinline__ unsigned short f2bf(float f) {
    unsigned int x = __builtin_bit_cast(unsigned int, f);
    unsigned int lsb = (x >> 16) & 1u;
    x += 0x7fffu + lsb;
    return (unsigned short)(x >> 16);
}

// packed f32x2 -> bf16x2 (RNE, matches f2bf bitwise): D[15:0]=bf16(lo), D[31:16]=bf16(hi)
__device__ __forceinline__ unsigned cvtpk(float lo, float hi) {
    unsigned d;
    asm("v_cvt_pk_bf16_f32 %0, %1, %2" : "=v"(d) : "v"(lo), "v"(hi));
    return d;
}

// DPP-based wave64 min-reduce (VALU-latency cross-lane; result valid in lane 63).
template<int CTRL>
__device__ __forceinline__ float dppmin_f(float x) {
    int xi = __builtin_bit_cast(int, x);
    int f = __builtin_amdgcn_update_dpp(xi, xi, CTRL, 0xf, 0xf, false);
    return fminf(x, __builtin_bit_cast(float, f));
}
__device__ __forceinline__ float wavemin_f(float x) {
    x = dppmin_f<0x111>(x);  // row_shr:1
    x = dppmin_f<0x112>(x);  // row_shr:2
    x = dppmin_f<0x114>(x);  // row_shr:4
    x = dppmin_f<0x118>(x);  // row_shr:8
    x = dppmin_f<0x142>(x);  // row_bcast:15
    x = dppmin_f<0x143>(x);  // row_bcast:31
    return x;
}

__global__ void k_init(float* acc) {
    if (threadIdx.x < 4) acc[threadIdx.x] = 0.0f;
}

// ---------------- pre-convert passes (run once; halve GEMM operand bytes) ----------------
__global__ __launch_bounds__(256) void k_cvt(const float* __restrict__ in,
                                             unsigned* __restrict__ out)
{
    const size_t id = (size_t)blockIdx.x * 256 + threadIdx.x;   // one int4 = 8 floats
    const float4 a = *(const float4*)(in + id * 8);
    const float4 b = *(const float4*)(in + id * 8 + 4);
    int4 o;
    o.x = (int)cvtpk(a.x, a.y); o.y = (int)cvtpk(a.z, a.w);
    o.z = (int)cvtpk(b.x, b.y); o.w = (int)cvtpk(b.z, b.w);
    *(int4*)(out + id * 4) = o;
}

// B [K][N] f32 -> [K/2][N] u32, dword = bf16(B[2kd][n]) | bf16(B[2kd+1][n])<<16
__global__ __launch_bounds__(256) void k_pack(const float* __restrict__ in,
                                              unsigned* __restrict__ out, int N)
{
    const int id = blockIdx.x * 256 + threadIdx.x;   // one int4 = 4 output dwords
    const int perRow = N >> 2;
    const int row = id / perRow;          // kd
    const int col = (id - row * perRow) << 2;
    const float4 r0 = *(const float4*)(in + (size_t)(2 * row) * N + col);
    const float4 r1 = *(const float4*)(in + (size_t)(2 * row + 1) * N + col);
    int4 o;
    o.x = (int)cvtpk(r0.x, r1.x); o.y = (int)cvtpk(r0.y, r1.y);
    o.z = (int)cvtpk(r0.z, r1.z); o.w = (int)cvtpk(r0.w, r1.w);
    *(int4*)(out + (size_t)row * N + col) = o;
}

// ============ bf16 MFMA GEMM: 64x64 tile, BK=32, LDS dbuf, prefetch-2, optional K-split ============
template<int OUT, int A_BF16, int SPLIT, int BPK>
__global__ __launch_bounds__(SPLIT ? 512 : 256) void k_mfma(
    const void* __restrict__ Araw,
    const void* __restrict__ Braw,
    const float* __restrict__ bias,
    float* __restrict__ Cf,
    unsigned short* __restrict__ Cb,
    const float* __restrict__ X,
    float* __restrict__ acc,
    int Nn, int K)
{
    __shared__ unsigned short As[SPLIT ? 2 : 1][2][64 * 40];  // [sub][buf][m*40+k]
    __shared__ unsigned int   Bd[SPLIT ? 2 : 1][2][64 * 20];  // [sub][buf][n*20+kd]
    __shared__ float          red[SPLIT ? 4096 : 1];
    const int t = threadIdx.x;
    const int sub = SPLIT ? (t >> 8) : 0;
    const int tt = SPLIT ? (t & 255) : t;
    const int w = tt >> 6;
    const int l = tt & 63;
    const int quad = l >> 4;
    const int r16 = l & 15;
    const int n0 = blockIdx.x * 64;
    const int m0 = blockIdx.y * 64;

    const int ar = tt >> 2, ac = (tt & 3) * 8;     // A staging
    const int kp = tt & 15, n4 = (tt >> 4) * 4;    // B staging

    const int kb = sub * (K >> SPLIT);
    const int ke = kb + (K >> SPLIT);

    f32x4 c0 = {0,0,0,0}, c1 = {0,0,0,0}, c2 = {0,0,0,0}, c3 = {0,0,0,0};

    int4   aI_0, aI_1, bP_0, bP_1;
    float4 aF0_0, aF1_0, bR0_0, bR1_0;
    float4 aF0_1, aF1_1, bR0_1, bR1_1;

    #define LOAD_T(S, k0)                                                              \
        do {                                                                           \
            if (A_BF16) {                                                              \
                const unsigned short* A = (const unsigned short*)Araw;                 \
                aI_##S = *(const int4*)(A + (size_t)(m0 + ar) * K + (k0) + ac);        \
            } else {                                                                   \
                const float* A = (const float*)Araw;                                   \
                aF0_##S = *(const float4*)(A + (size_t)(m0 + ar) * K + (k0) + ac);     \
                aF1_##S = *(const float4*)(A + (size_t)(m0 + ar) * K + (k0) + ac + 4); \
            }                                                                          \
            if (BPK) {                                                                 \
                const unsigned* Bp = (const unsigned*)Braw;                            \
                bP_##S = *(const int4*)(Bp + (size_t)(((k0) >> 1) + kp) * Nn + n0 + n4);\
            } else {                                                                   \
                const float* B = (const float*)Braw;                                   \
                bR0_##S = *(const float4*)(B + (size_t)((k0) + 2 * kp) * Nn + n0 + n4);\
                bR1_##S = *(const float4*)(B + (size_t)((k0) + 2 * kp + 1) * Nn + n0 + n4);\
            }                                                                          \
        } while (0)

    #define STORE_T(S, buf)                                                            \
        do {                                                                           \
            if (A_BF16) {                                                              \
                *(int4*)(&As[sub][buf][ar * 40 + ac]) = aI_##S;                        \
            } else {                                                                   \
                int4 p;                                                                \
                p.x = (int)cvtpk(aF0_##S.x, aF0_##S.y);                                \
                p.y = (int)cvtpk(aF0_##S.z, aF0_##S.w);                                \
                p.z = (int)cvtpk(aF1_##S.x, aF1_##S.y);                                \
                p.w = (int)cvtpk(aF1_##S.z, aF1_##S.w);                                \
                *(int4*)(&As[sub][buf][ar * 40 + ac]) = p;                             \
            }                                                                          \
            if (BPK) {                                                                 \
                Bd[sub][buf][(n4 + 0) * 20 + kp] = (unsigned)bP_##S.x;                 \
                Bd[sub][buf][(n4 + 1) * 20 + kp] = (unsigned)bP_##S.y;                 \
                Bd[sub][buf][(n4 + 2) * 20 + kp] = (unsigned)bP_##S.z;                 \
                Bd[sub][buf][(n4 + 3) * 20 + kp] = (unsigned)bP_##S.w;                 \
            } else {                                                                   \
                const float bl[4] = {bR0_##S.x, bR0_##S.y, bR0_##S.z, bR0_##S.w};      \
                const float bh[4] = {bR1_##S.x, bR1_##S.y, bR1_##S.z, bR1_##S.w};      \
                _Pragma("unroll")                                                      \
                for (int i = 0; i < 4; ++i)                                            \
                    Bd[sub][buf][(n4 + i) * 20 + kp] = cvtpk(bl[i], bh[i]);            \
            }                                                                          \
        } while (0)

    #define COMP(buf)                                                                  \
        do {                                                                           \
            bf16x8 bf = *(const bf16x8*)(&Bd[sub][buf][(w * 16 + r16) * 20 + quad * 4]);\
            bf16x8 a0 = *(const bf16x8*)(&As[sub][buf][(0  + r16) * 40 + quad * 8]);   \
            bf16x8 a1 = *(const bf16x8*)(&As[sub][buf][(16 + r16) * 40 + quad * 8]);   \
            bf16x8 a2 = *(const bf16x8*)(&As[sub][buf][(32 + r16) * 40 + quad * 8]);   \
            bf16x8 a3 = *(const bf16x8*)(&As[sub][buf][(48 + r16) * 40 + quad * 8]);   \
            c0 = __builtin_amdgcn_mfma_f32_16x16x32_bf16(a0, bf, c0, 0, 0, 0);         \
            c1 = __builtin_amdgcn_mfma_f32_16x16x32_bf16(a1, bf, c1, 0, 0, 0);         \
            c2 = __builtin_amdgcn_mfma_f32_16x16x32_bf16(a2, bf, c2, 0, 0, 0);         \
            c3 = __builtin_amdgcn_mfma_f32_16x16x32_bf16(a3, bf, c3, 0, 0, 0);         \
        } while (0)

    // prologue: tiles kb, kb+32 in flight; tile kb staged to buf0
    LOAD_T(0, kb);
    LOAD_T(1, kb + 32);
    STORE_T(0, 0);
    int cur = 0;
    // main loop: two tiles per trip, one barrier per tile
    for (int k0 = kb; k0 < ke; k0 += 64) {
        if (k0 + 64 < ke) LOAD_T(0, k0 + 64);
        __syncthreads();            // buf[cur] (tile k0) ready; prior reads of buf[cur^1] done
        COMP(cur);
        STORE_T(1, cur ^ 1);        // tile k0+32 (loads issued one tile ago)
        cur ^= 1;
        if (k0 + 96 < ke) LOAD_T(1, k0 + 96);
        __syncthreads();            // buf[cur] (tile k0+32) ready
        COMP(cur);
        if (k0 + 64 < ke) { STORE_T(0, cur ^ 1); cur ^= 1; }
    }
    #undef LOAD_T
    #undef STORE_T
    #undef COMP

    f32x4 frags[4] = {c0, c1, c2, c3};

    if (SPLIT) {
        if (sub == 1) {
            #pragma unroll
            for (int f = 0; f < 4; ++f)
                #pragma unroll
                for (int rg = 0; rg < 4; ++rg)
                    red[(f * 16 + quad * 4 + rg) * 64 + w * 16 + r16] = frags[f][rg];
        }
        __syncthreads();
        if (sub == 1) return;
        #pragma unroll
        for (int f = 0; f < 4; ++f)
            #pragma unroll
            for (int rg = 0; rg < 4; ++rg)
                frags[f][rg] += red[(f * 16 + quad * 4 + rg) * 64 + w * 16 + r16];
    }

    const int col = n0 + w * 16 + r16;
    const float bval = bias[col];
    float local = 0.f;
    #pragma unroll
    for (int f = 0; f < 4; ++f) {
        #pragma unroll
        for (int rg = 0; rg < 4; ++rg) {
            const int row = m0 + f * 16 + quad * 4 + rg;  // C/D: col=lane&15, row=quad*4+reg (m89)
            const float v = frags[f][rg] + bval;
            if (OUT == 0) {
                Cf[(size_t)row * Nn + col] = fmaxf(v, 0.f);
            } else if (OUT == 1) {
                Cb[(size_t)row * Nn + col] = f2bf(fmaxf(v, 0.f));
            } else {
                const float d = X[(size_t)row * Nn + col] - v;
                local += d * d;
            }
        }
    }
    if (OUT == 2) {
        #pragma unroll
        for (int off = 32; off; off >>= 1) local += __shfl_xor(local, off);
        if (l == 0) atomicAdd(acc, local);
    }
}

// ============ GEMM4 128x128 tile: h2b[512,K]@Wd2p -> fused MSE vs X (no C store) ============
// 512 threads = 8 waves (2 row x 4 col); wave owns 64x32 output (8 MFMA + 6 ds_read/K-step).
// Grid (Nn/128, 512/128) = 256 blocks = 1/CU: 64 iterations/CU vs 256 with 64^2 tiles,
// and panel re-read traffic 528 -> 280 MB.
__global__ __launch_bounds__(512) void k_mfma4(
    const unsigned short* __restrict__ A,   // [512][K] bf16
    const unsigned* __restrict__ Bp,        // [K/2][Nn] k-pair packed
    const float* __restrict__ bias,
    const float* __restrict__ X,
    float* __restrict__ acc,
    int Nn, int K)
{
    __shared__ unsigned short As[2][128 * 40];  // [buf][m*40+k] (stride 40 ush)
    __shared__ unsigned int   Bd[2][128 * 20];  // [buf][n*20+kd] (stride 20 dw)
    const int t = threadIdx.x;
    const int w = t >> 6, l = t & 63;
    const int quad = l >> 4, r16 = l & 15;
    const int wr = w >> 2, wc = w & 3;          // wave 2x4 grid
    const int n0 = blockIdx.x * 128;
    const int m0 = blockIdx.y * 128;
    const int ar = t >> 2, ac = (t & 3) * 8;    // A staging: 128 rows x 32 k
    const int kp = t & 15, n4 = (t >> 4) * 4;   // B staging: 16 kd x 128 n

    f32x4 c00 = {0,0,0,0}, c01 = {0,0,0,0}, c10 = {0,0,0,0}, c11 = {0,0,0,0},
          c20 = {0,0,0,0}, c21 = {0,0,0,0}, c30 = {0,0,0,0}, c31 = {0,0,0,0};

    int4 aI_0, aI_1, bP_0, bP_1;

    #define LOAD4(S, k0)                                                               \
        do {                                                                           \
            aI_##S = *(const int4*)(A + (size_t)(m0 + ar) * K + (k0) + ac);            \
            bP_##S = *(const int4*)(Bp + (size_t)(((k0) >> 1) + kp) * Nn + n0 + n4);   \
        } while (0)

    #define STORE4(S, buf)                                                             \
        do {                                                                           \
            *(int4*)(&As[buf][ar * 40 + ac]) = aI_##S;                                 \
            Bd[buf][(n4 + 0) * 20 + kp] = (unsigned)bP_##S.x;                          \
            Bd[buf][(n4 + 1) * 20 + kp] = (unsigned)bP_##S.y;                          \
            Bd[buf][(n4 + 2) * 20 + kp] = (unsigned)bP_##S.z;                          \
            Bd[buf][(n4 + 3) * 20 + kp] = (unsigned)bP_##S.w;                          \
        } while (0)

    #define COMP4(buf)                                                                 \
        do {                                                                           \
            bf16x8 b0 = *(const bf16x8*)(&Bd[buf][(wc * 32 +  0 + r16) * 20 + quad * 4]);\
            bf16x8 b1 = *(const bf16x8*)(&Bd[buf][(wc * 32 + 16 + r16) * 20 + quad * 4]);\
            bf16x8 a0 = *(const bf16x8*)(&As[buf][(wr * 64 +  0 + r16) * 40 + quad * 8]);\
            bf16x8 a1 = *(const bf16x8*)(&As[buf][(wr * 64 + 16 + r16) * 40 + quad * 8]);\
            bf16x8 a2 = *(const bf16x8*)(&As[buf][(wr * 64 + 32 + r16) * 40 + quad * 8]);\
            bf16x8 a3 = *(const bf16x8*)(&As[buf][(wr * 64 + 48 + r16) * 40 + quad * 8]);\
            c00 = __builtin_amdgcn_mfma_f32_16x16x32_bf16(a0, b0, c00, 0, 0, 0);       \
            c01 = __builtin_amdgcn_mfma_f32_16x16x32_bf16(a0, b1, c01, 0, 0, 0);       \
            c10 = __builtin_amdgcn_mfma_f32_16x16x32_bf16(a1, b0, c10, 0, 0, 0);       \
            c11 = __builtin_amdgcn_mfma_f32_16x16x32_bf16(a1, b1, c11, 0, 0, 0);       \
            c20 = __builtin_amdgcn_mfma_f32_16x16x32_bf16(a2, b0, c20, 0, 0, 0);       \
            c21 = __builtin_amdgcn_mfma_f32_16x16x32_bf16(a2, b1, c21, 0, 0, 0);       \
            c30 = __builtin_amdgcn_mfma_f32_16x16x32_bf16(a3, b0, c30, 0, 0, 0);       \
            c31 = __builtin_amdgcn_mfma_f32_16x16x32_bf16(a3, b1, c31, 0, 0, 0);       \
        } while (0)

    LOAD4(0, 0);
    LOAD4(1, 32);
    STORE4(0, 0);
    int cur = 0;
    for (int k0 = 0; k0 < K; k0 += 64) {
        if (k0 + 64 < K) LOAD4(0, k0 + 64);
        __syncthreads();
        COMP4(cur);
        STORE4(1, cur ^ 1);
        cur ^= 1;
        if (k0 + 96 < K) LOAD4(1, k0 + 96);
        __syncthreads();
        COMP4(cur);
        if (k0 + 64 < K) { STORE4(0, cur ^ 1); cur ^= 1; }
    }
    #undef LOAD4
    #undef STORE4
    #undef COMP4

    const int col0 = n0 + wc * 32 + r16;
    const int col1 = col0 + 16;
    const float bv0 = bias[col0];
    const float bv1 = bias[col1];
    f32x4 f0[4] = {c00, c10, c20, c30};
    f32x4 f1[4] = {c01, c11, c21, c31};
    float local = 0.f;
    #pragma unroll
    for (int f = 0; f < 4; ++f) {
        #pragma unroll
        for (int rg = 0; rg < 4; ++rg) {
            const int row = m0 + wr * 64 + f * 16 + quad * 4 + rg;
            const float d0 = X[(size_t)row * Nn + col0] - (f0[f][rg] + bv0);
            const float d1 = X[(size_t)row * Nn + col1] - (f1[f][rg] + bv1);
            local += d0 * d0 + d1 * d1;
        }
    }
    #pragma unroll
    for (int off = 32; off; off >>= 1) local += __shfl_xor(local, off);
    if (l == 0) atomicAdd(acc, local);
}

// ============ GEMM2 (latent = h1@We2+b2), fp32 VALU, 64x64 tile, in-block 2-way K-split ============
__global__ __launch_bounds__(512) void k_gemm2(
    const float* __restrict__ A,     // [512,2048]
    const float* __restrict__ B,     // [2048,256]
    const float* __restrict__ bias,  // [256]
    float* __restrict__ C)           // [512,256]
{
    __shared__ float AT[2][32 * 68];
    __shared__ float Bs[2][32 * 68];
    __shared__ float red[64 * 64];
    const int t = threadIdx.x;
    const int sub = t >> 8, tt = t & 255;
    const int m0 = blockIdx.y * 64, n0 = blockIdx.x * 64;
    const int ti = tt >> 4, tj = tt & 15;
    const int ar = tt >> 2, ac = (tt & 3) * 8;
    const int bk = tt >> 3, bc = (tt & 7) * 8;
    const int kbase = sub * 1024;
    float accm[4][4] = {{0.f}};

    for (int k0 = 0; k0 < 1024; k0 += 32) {
        const int kk0 = kbase + k0;
        const float4 a0 = *(const float4*)(A + (size_t)(m0 + ar) * HENC + kk0 + ac);
        const float4 a1 = *(const float4*)(A + (size_t)(m0 + ar) * HENC + kk0 + ac + 4);
        const float av[8] = {a0.x, a0.y, a0.z, a0.w, a1.x, a1.y, a1.z, a1.w};
        #pragma unroll
        for (int e = 0; e < 8; ++e) AT[sub][(ac + e) * 68 + ar] = av[e];
        *(float4*)(&Bs[sub][bk * 68 + bc])     = *(const float4*)(B + (size_t)(kk0 + bk) * EMB + n0 + bc);
        *(float4*)(&Bs[sub][bk * 68 + bc + 4]) = *(const float4*)(B + (size_t)(kk0 + bk) * EMB + n0 + bc + 4);
        __syncthreads();
        #pragma unroll 8
        for (int kk = 0; kk < 32; ++kk) {
            const float4 a = *(const float4*)(&AT[sub][kk * 68 + ti * 4]);
            const float4 b = *(const float4*)(&Bs[sub][kk * 68 + tj * 4]);
            accm[0][0] += a.x * b.x; accm[0][1] += a.x * b.y; accm[0][2] += a.x * b.z; accm[0][3] += a.x * b.w;
            accm[1][0] += a.y * b.x; accm[1][1] += a.y * b.y; accm[1][2] += a.y * b.z; accm[1][3] += a.y * b.w;
            accm[2][0] += a.z * b.x; accm[2][1] += a.z * b.y; accm[2][2] += a.z * b.z; accm[2][3] += a.z * b.w;
            accm[3][0] += a.w * b.x; accm[3][1] += a.w * b.y; accm[3][2] += a.w * b.z; accm[3][3] += a.w * b.w;
        }
        __syncthreads();
    }

    if (sub == 1) {
        #pragma unroll
        for (int i = 0; i < 4; ++i)
            #pragma unroll
            for (int j = 0; j < 4; ++j)
                red[(ti * 4 + i) * 64 + tj * 4 + j] = accm[i][j];
    }
    __syncthreads();
    if (sub == 0) {
        #pragma unroll
        for (int i = 0; i < 4; ++i) {
            const int row = m0 + ti * 4 + i;
            #pragma unroll
            for (int j = 0; j < 4; ++j) {
                const int colj = n0 + tj * 4 + j;
                const float v = (accm[i][j] + red[(ti * 4 + i) * 64 + tj * 4 + j]) + bias[colj];
                C[(size_t)row * EMB + colj] = v;
            }
        }
    }
}

// ---------------- row norms per branch ----------------
__global__ void k_sn(const float* __restrict__ latent, float* __restrict__ sn) {
    const int idx = blockIdx.x * blockDim.x + threadIdx.x;
    if (idx >= 1024) return;
    const int br = idx >> 9, r = idx & 511;
    const float* p = latent + (size_t)r * EMB + br * BR;
    float s = 0.f;
    for (int c = 0; c < BR; ++c) s += p[c] * p[c];
    sn[br * 512 + r] = s;
}

// ---------------- full distance matrix (Gram formula, as reference MST path) ----------------
__global__ __launch_bounds__(256) void k_dist(const float* __restrict__ latent,
                                              const float* __restrict__ sn,
                                              float* __restrict__ D)
{
    const int branch = blockIdx.y;
    const int ti = blockIdx.x >> 3, tj = blockIdx.x & 7;
    const int i0 = ti * 64, j0 = tj * 64;
    __shared__ float LiT[64 * 65];
    __shared__ float LjT[64 * 65];
    const int t = threadIdx.x;
    const int pi = t >> 4, pj = t & 15;
    float dot[4][4] = {{0.f}};

    for (int kc = 0; kc < BR; kc += 64) {
        for (int idx = t; idx < 1024; idx += 256) {
            const int r = idx >> 4, kq = (idx & 15) * 4;
            const float4 vi = *(const float4*)(latent + (size_t)(i0 + r) * EMB + branch * BR + kc + kq);
            const float4 vj = *(const float4*)(latent + (size_t)(j0 + r) * EMB + branch * BR + kc + kq);
            LiT[(kq + 0) * 65 + r] = vi.x; LiT[(kq + 1) * 65 + r] = vi.y;
            LiT[(kq + 2) * 65 + r] = vi.z; LiT[(kq + 3) * 65 + r] = vi.w;
            LjT[(kq + 0) * 65 + r] = vj.x; LjT[(kq + 1) * 65 + r] = vj.y;
            LjT[(kq + 2) * 65 + r] = vj.z; LjT[(kq + 3) * 65 + r] = vj.w;
        }
        __syncthreads();
        for (int k = 0; k < 64; ++k) {
            float a[4], b[4];
            #pragma unroll
            for (int i = 0; i < 4; ++i) a[i] = LiT[k * 65 + pi * 4 + i];
            #pragma unroll
            for (int j = 0; j < 4; ++j) b[j] = LjT[k * 65 + pj * 4 + j];
            #pragma unroll
            for (int i = 0; i < 4; ++i)
                #pragma unroll
                for (int j = 0; j < 4; ++j) dot[i][j] += a[i] * b[j];
        }
        __syncthreads();
    }

    const float* snb = sn + branch * 512;
    float* Db = D + (size_t)branch * 512 * 512;
    #pragma unroll
    for (int i = 0; i < 4; ++i) {
        const int gi = i0 + pi * 4 + i;
        #pragma unroll
        for (int j = 0; j < 4; ++j) {
            const int gj = j0 + pj * 4 + j;
            const float d2 = snb[gi] + snb[gj] - 2.0f * dot[i][j];
            Db[(size_t)gi * 512 + gj] = sqrtf(fmaxf(d2, 0.0f));
        }
    }
}

// ---------------- Boruvka MST: parallel rounds replace Prim's 511-long serial chain ----------------
__global__ __launch_bounds__(1024) void k_prim(const float* __restrict__ D,
                                               float2* __restrict__ mstb,
                                               float* __restrict__ acc)
{
    const int branch = blockIdx.x;
    const float* Db = D + (size_t)branch * 512 * 512;
    const int t = threadIdx.x;
    const int wid = t >> 6;      // wave id 0..15
    const int l = t & 63;
    const int l8 = l << 3;

    __shared__ unsigned short comp16[512];   // component label per vertex (a root vertex id)
    __shared__ unsigned       parent[512];   // hooking forest, per round
    __shared__ unsigned short minj[512];     // per-vertex argmin column
    __shared__ unsigned       minwb[512];    // per-vertex min weight bits (f32, positive -> u32 ordered)
    __shared__ unsigned       cminw[512];    // per-component min weight bits
    __shared__ unsigned       csrc[512];     // per-component winning vertex
    __shared__ float          elist[512];    // emitted MST edge weights
    __shared__ int            ne_sh;

    const unsigned SENT = 0x7f61b1e6u;       // bits of 3.0e38f (masked-out sentinel)

    for (int i = t; i < 512; i += 1024) comp16[i] = (unsigned short)i;
    if (t == 0) ne_sh = 0;

    // prewarm D into this XCD's L2 (1 MB, every 64B line)
    float s = 0.f;
    for (int i = t; i < 16384; i += 1024) s += Db[(size_t)i * 16];
    if (s == -1e30f) acc[3] = s;  // never true; keeps prewarm loads alive
    __syncthreads();

    int ne = 0;
    for (int round = 0; round < 12 && ne < 511; ++round) {
        for (int i = t; i < 512; i += 1024) {
            cminw[i] = 0xFFFFFFFFu;
            csrc[i]  = 0xFFFFFFFFu;
            parent[i] = (unsigned)i;
        }
        __syncthreads();

        // hoist this lane's component slice (comp16 is frozen during the scan phase)
        const u16x8 cj = *(const u16x8*)(&comp16[l8]);

        // per-vertex masked argmin over its row; one wave per vertex, vertices independent
        for (int v = wid; v < 512; v += 16) {
            const unsigned cv = comp16[v];   // uniform-address LDS broadcast
            const float4 d0 = *(const float4*)(Db + (size_t)v * 512 + l8);
            const float4 d1 = *(const float4*)(Db + (size_t)v * 512 + l8 + 4);
            const float vv[8] = {d0.x, d0.y, d0.z, d0.w, d1.x, d1.y, d1.z, d1.w};
            float best = 3.0e38f; int bi = 0;
            #pragma unroll
            for (int e = 0; e < 8; ++e) {
                const float m = ((unsigned)cj[e] == cv) ? 3.0e38f : vv[e];
                if (m < best) { best = m; bi = e; }
            }
            const float gr = wavemin_f(best);
            const unsigned gbits = (unsigned)__builtin_amdgcn_readlane(
                __builtin_bit_cast(int, gr), 63);
            const float g = __builtin_bit_cast(float, gbits);
            const unsigned long long msk = __ballot(best == g);
            const int src = __ffsll((long long)msk) - 1;
            const int jg = __builtin_amdgcn_readlane(l8 + bi, src);
            if (l == 0) {
                minwb[v] = (gbits == SENT) ? 0xFFFFFFFFu : gbits;
                minj[v]  = (unsigned short)jg;
                if (gbits != SENT) atomicMin(&cminw[cv], gbits);
            }
        }
        __syncthreads();

        // per-component winner vertex (any vertex attaining the component min)
        for (int v = t; v < 512; v += 1024) {
            const unsigned mw = minwb[v];
            if (mw != 0xFFFFFFFFu && mw == cminw[comp16[v]])
                atomicMin(&csrc[comp16[v]], (unsigned)v);
        }
        __syncthreads();

        // emit + hook per component root
        for (int c = t; c < 512; c += 1024) {
            const unsigned sv = csrc[c];
            if (sv != 0xFFFFFFFFu) {
                const unsigned wbits = cminw[c];
                const unsigned j = minj[sv];
                const unsigned c2 = comp16[j];
                const bool mutual = (cminw[c2] == wbits);  // distinct weights -> same edge
                if (!mutual || (unsigned)c < c2)
                    elist[atomicAdd(&ne_sh, 1)] = __builtin_bit_cast(float, wbits);
                parent[c] = (mutual && (unsigned)c < c2) ? (unsigned)c : c2;
            }
        }
        __syncthreads();

        // pointer jumping (chains <= 512 -> 9 doubling passes; u32 races are benign/monotone)
        for (int pj = 0; pj < 9; ++pj) {
            for (int i = t; i < 512; i += 1024) parent[i] = parent[parent[i]];
            __syncthreads();
        }
        for (int i = t; i < 512; i += 1024) comp16[i] = (unsigned short)parent[comp16[i]];
        __syncthreads();
        ne = ne_sh;
    }

    for (int i = t; i < 511; i += 1024) {
        const float w = elist[i];
        mstb[branch * 511 + i] = make_float2(w, ATOLC + RTOL * fabsf(w));
    }
}

// ---------------- loss: pdist (diff formula) + LDS-staged band scan + |ETA - d| ----------------
__global__ __launch_bounds__(256) void k_loss(const float* __restrict__ latent,
                                              const float2* __restrict__ mstb,
                                              float* __restrict__ acc)
{
    const int branch = blockIdx.y;
    int bid = blockIdx.x, ti = 0;
    while (bid >= 8 - ti) { bid -= 8 - ti; ti++; }
    const int tj = ti + bid;
    const int i0 = ti * 64, j0 = tj * 64;
    __shared__ float LiT[64 * 65];
    __shared__ float LjT[64 * 65];
    __shared__ float2 msh[511];          // band list staged once (was: 511 global re-reads/thread)
    const int t = threadIdx.x;
    const int pi = t >> 4, pj = t & 15;
    float d2[16];
    #pragma unroll
    for (int p = 0; p < 16; ++p) d2[p] = 0.f;

    // stage mstb -> LDS; visibility covered by the first __syncthreads in the kc loop
    {
        const float2* mbp = mstb + branch * 511;
        for (int i = t; i < 511; i += 256) msh[i] = mbp[i];
    }

    for (int kc = 0; kc < BR; kc += 64) {
        for (int idx = t; idx < 1024; idx += 256) {
            const int r = idx >> 4, kq = (idx & 15) * 4;
            const float4 vi = *(const float4*)(latent + (size_t)(i0 + r) * EMB + branch * BR + kc + kq);
            const float4 vj = *(const float4*)(latent + (size_t)(j0 + r) * EMB + branch * BR + kc + kq);
            LiT[(kq + 0) * 65 + r] = vi.x; LiT[(kq + 1) * 65 + r] = vi.y;
            LiT[(kq + 2) * 65 + r] = vi.z; LiT[(kq + 3) * 65 + r] = vi.w;
            LjT[(kq + 0) * 65 + r] = vj.x; LjT[(kq + 1) * 65 + r] = vj.y;
            LjT[(kq + 2) * 65 + r] = vj.z; LjT[(kq + 3) * 65 + r] = vj.w;
        }
        __syncthreads();
        for (int k = 0; k < 64; ++k) {
            float a[4], b[4];
            #pragma unroll
            for (int i = 0; i < 4; ++i) a[i] = LiT[k * 65 + pi * 4 + i];
            #pragma unroll
            for (int j = 0; j < 4; ++j) b[j] = LjT[k * 65 + pj * 4 + j];
            #pragma unroll
            for (int i = 0; i < 4; ++i)
                #pragma unroll
                for (int j = 0; j < 4; ++j) {
                    const float df = a[i] - b[j];
                    d2[i * 4 + j] += df * df;
                }
        }
        __syncthreads();
    }

    float dd[16]; int valid[16];
    #pragma unroll
    for (int i = 0; i < 4; ++i)
        #pragma unroll
        for (int j = 0; j < 4; ++j) {
            const int gi = i0 + pi * 4 + i, gj = j0 + pj * 4 + j;
            dd[i * 4 + j] = sqrtf(d2[i * 4 + j]);
            valid[i * 4 + j] = (gi < gj);
        }
    unsigned int mm = 0;
    #pragma unroll 4
    for (int m = 0; m < 511; ++m) {
        const float2 mv = msh[m];     // LDS broadcast read; pipelines across unrolled iters
        #pragma unroll
        for (int p = 0; p < 16; ++p)
            if (fabsf(dd[p] - mv.x) <= mv.y) mm |= (1u << p);
    }
    float sloc = 0.f;
    #pragma unroll
    for (int p = 0; p < 16; ++p)
        if (valid[p] && ((mm >> p) & 1u)) sloc += fabsf(ETA - dd[p]);
    #pragma unroll
    for (int off = 32; off; off >>= 1) sloc += __shfl_xor(sloc, off);
    if ((t & 63) == 0) atomicAdd(&acc[1], sloc);
}

__global__ void k_final(const float* __restrict__ acc, float* __restrict__ out) {
    if (threadIdx.x == 0) {
        out[0] = acc[0] / (float)((size_t)NPTS * DIN) + acc[1];
    }
}

extern "C" void kernel_launch(void* const* d_in, const int* in_sizes, int n_in,
                              void* d_out, int out_size, void* d_ws, size_t ws_size,
                              hipStream_t stream) {
    (void)in_sizes; (void)n_in; (void)out_size;
    const float* x   = (const float*)d_in[0];
    const float* We1 = (const float*)d_in[1];
    const float* be1 = (const float*)d_in[2];
    const float* We2 = (const float*)d_in[3];
    const float* be2 = (const float*)d_in[4];
    const float* Wd1 = (const float*)d_in[5];
    const float* bd1 = (const float*)d_in[6];
    const float* Wd2 = (const float*)d_in[7];
    const float* bd2 = (const float*)d_in[8];

    // ws layout:
    //   low region: acc @0, sn @4096, mstb @8192, latent @16384 (512 KB)
    //   h1 @540672 (4 MB) / Dm aliases / h2b aliases
    //   fast path adds: xb @8MB (8MB), We1p @16MB (32MB), Wd2p @48MB (32MB), Wd1p @80MB (1MB)
    char* ws = (char*)d_ws;
    float*          acc    = (float*)(ws);
    float*          sn     = (float*)(ws + 4096);
    float2*         mstb   = (float2*)(ws + 8192);
    float*          latent = (float*)(ws + 16384);
    float*          h1     = (float*)(ws + 540672);
    float*          Dm     = (float*)(ws + 540672);
    unsigned short* h2b    = (unsigned short*)(ws + 540672);

    const size_t MB = 1024u * 1024u;
    unsigned*       xb   = (unsigned*)(ws + 8 * MB);
    unsigned*       We1p = (unsigned*)(ws + 16 * MB);
    unsigned*       Wd2p = (unsigned*)(ws + 48 * MB);
    unsigned*       Wd1p = (unsigned*)(ws + 80 * MB);
    const bool fast = ws_size >= 81 * MB;

    k_init<<<1, 64, 0, stream>>>(acc);

    if (fast) {
        // pre-convert operands to bf16 / k-pair-packed dwords
        k_cvt <<<2048, 256, 0, stream>>>(x, xb);
        k_pack<<<8192, 256, 0, stream>>>(We1, We1p, HENC);
        k_pack<<<8192, 256, 0, stream>>>(Wd2, Wd2p, DIN);
        k_pack<<< 256, 256, 0, stream>>>(Wd1, Wd1p, HDEC);

        k_mfma<0, 1, 1, 1><<<dim3(HENC / 64, NPTS / 64), 512, 0, stream>>>(xb, We1p, be1, h1, nullptr, nullptr, nullptr, HENC, DIN);
        k_gemm2<<<dim3(EMB / 64, NPTS / 64), 512, 0, stream>>>(h1, We2, be2, latent);
        k_sn<<<4, 256, 0, stream>>>(latent, sn);
        k_dist<<<dim3(64, 2), 256, 0, stream>>>(latent, sn, Dm);
        k_prim<<<2, 1024, 0, stream>>>(Dm, mstb, acc);
        k_loss<<<dim3(36, 2), 256, 0, stream>>>(latent, mstb, acc);
        k_mfma<1, 0, 1, 1><<<dim3(HDEC / 64, NPTS / 64), 512, 0, stream>>>(latent, Wd1p, bd1, nullptr, h2b, nullptr, nullptr, HDEC, EMB);
        // GEMM4: 128x128 tile, 1 block/CU, fused MSE
        k_mfma4<<<dim3(DIN / 128, NPTS / 128), 512, 0, stream>>>(h2b, Wd2p, bd2, x, acc, DIN, HDEC);
    } else {
        // fallback: round-4 structure (f32 operands, cvt_pk in staging)
        k_mfma<0, 0, 1, 0><<<dim3(HENC / 64, NPTS / 64), 512, 0, stream>>>(x, We1, be1, h1, nullptr, nullptr, nullptr, HENC, DIN);
        k_gemm2<<<dim3(EMB / 64, NPTS / 64), 512, 0, stream>>>(h1, We2, be2, latent);
        k_sn<<<4, 256, 0, stream>>>(latent, sn);
        k_dist<<<dim3(64, 2), 256, 0, stream>>>(latent, sn, Dm);
        k_prim<<<2, 1024, 0, stream>>>(Dm, mstb, acc);
        k_loss<<<dim3(36, 2), 256, 0, stream>>>(latent, mstb, acc);
        k_mfma<1, 0, 1, 0><<<dim3(HDEC / 64, NPTS / 64), 512, 0, stream>>>(latent, Wd1, bd1, nullptr, h2b, nullptr, nullptr, HDEC, EMB);
        k_mfma<2, 1, 0, 0><<<dim3(DIN / 64, NPTS / 64), 256, 0, stream>>>(h2b, Wd2, bd2, nullptr, nullptr, x, acc, DIN, HDEC);
    }
    k_final<<<1, 64, 0, stream>>>(acc, (float*)d_out);
}